// Round 1
// baseline (1153.295 us; speedup 1.0000x reference)
//
#include <hip/hip_runtime.h>
#include <hip/hip_bf16.h>
#include <math.h>

#define BB   2
#define SS   2048
#define DIM  1024
#define NH   16
#define HD   64
#define MTOT (BB * SS)   // 4096

// ---------------------------------------------------------------------------
// SGEMM: Y = X @ W.  X: M x 1024 row-major, W: 1024 x 1024 row-major.
// 128x128 tile, BK=16, 256 threads, 8x8 per thread (2x2 grid of 4x4).
// blockIdx.z selects (W,Y) so Q/K/V projections run as one launch.
// ---------------------------------------------------------------------------
__global__ __launch_bounds__(256) void sgemm3_kernel(
    const float* __restrict__ X,
    const float* __restrict__ W0, const float* __restrict__ W1, const float* __restrict__ W2,
    float* __restrict__ Y0, float* __restrict__ Y1, float* __restrict__ Y2)
{
    const int z = blockIdx.z;
    const float* __restrict__ W = (z == 0) ? W0 : (z == 1) ? W1 : W2;
    float* __restrict__ Y       = (z == 0) ? Y0 : (z == 1) ? Y1 : Y2;

    const int K = 1024, N = 1024;
    const int m0 = blockIdx.y * 128;
    const int n0 = blockIdx.x * 128;
    const int tid = threadIdx.x;
    const int tr = tid >> 4;   // 0..15
    const int tc = tid & 15;   // 0..15

    __shared__ float As[16][132];   // As[kk][m]  (X tile, transposed on store)
    __shared__ float Bs[16][132];   // Bs[kk][n]

    float acc[8][8];
#pragma unroll
    for (int i = 0; i < 8; i++)
#pragma unroll
        for (int j = 0; j < 8; j++) acc[i][j] = 0.f;

    for (int k0 = 0; k0 < K; k0 += 16) {
        // stage X tile (128 rows x 16 cols), transposed into As
#pragma unroll
        for (int i = 0; i < 2; i++) {
            int id  = tid + i * 256;       // 0..511
            int row = id >> 2;             // 0..127
            int c4  = (id & 3) * 4;        // 0,4,8,12
            float4 xv = *(const float4*)(X + (size_t)(m0 + row) * K + k0 + c4);
            As[c4 + 0][row] = xv.x;
            As[c4 + 1][row] = xv.y;
            As[c4 + 2][row] = xv.z;
            As[c4 + 3][row] = xv.w;
        }
        // stage W tile (16 rows x 128 cols)
#pragma unroll
        for (int i = 0; i < 2; i++) {
            int id  = tid + i * 256;       // 0..511
            int row = id >> 5;             // 0..15
            int c4  = (id & 31) * 4;       // 0..124
            *(float4*)(&Bs[row][c4]) = *(const float4*)(W + (size_t)(k0 + row) * N + n0 + c4);
        }
        __syncthreads();

#pragma unroll
        for (int kk = 0; kk < 16; kk++) {
            float4 a0 = *(const float4*)(&As[kk][tr * 4]);
            float4 a1 = *(const float4*)(&As[kk][64 + tr * 4]);
            float4 b0 = *(const float4*)(&Bs[kk][tc * 4]);
            float4 b1 = *(const float4*)(&Bs[kk][64 + tc * 4]);
            float a[8] = {a0.x, a0.y, a0.z, a0.w, a1.x, a1.y, a1.z, a1.w};
            float b[8] = {b0.x, b0.y, b0.z, b0.w, b1.x, b1.y, b1.z, b1.w};
#pragma unroll
            for (int i = 0; i < 8; i++)
#pragma unroll
                for (int j = 0; j < 8; j++)
                    acc[i][j] = fmaf(a[i], b[j], acc[i][j]);
        }
        __syncthreads();
    }

    // epilogue: 16 float4 stores per thread
#pragma unroll
    for (int gi = 0; gi < 2; gi++)
#pragma unroll
        for (int i = 0; i < 4; i++) {
            int row = m0 + gi * 64 + tr * 4 + i;
#pragma unroll
            for (int gj = 0; gj < 2; gj++) {
                float4 o4 = make_float4(acc[gi * 4 + i][gj * 4 + 0],
                                        acc[gi * 4 + i][gj * 4 + 1],
                                        acc[gi * 4 + i][gj * 4 + 2],
                                        acc[gi * 4 + i][gj * 4 + 3]);
                *(float4*)(Y + (size_t)row * N + n0 + gj * 64 + tc * 4) = o4;
            }
        }
}

// ---------------------------------------------------------------------------
// Attention with the reference's per-iteration division:
//   m_new = max(m, rowmax(S));  alpha = exp(m - m_new);  P = exp(S - m_new)
//   l_new = alpha*l + rowsum(P)
//   O     = (alpha*O + P @ V) / l_new          <-- divided EVERY kv step
// kv block = 64 (semantically required), q tile = 64 rows per block.
// q/k/v/o layout: (B, S, H*D) row-major; per-(b,h) rows have stride DIM.
// ---------------------------------------------------------------------------
__global__ __launch_bounds__(256) void attn_kernel(
    const float* __restrict__ q, const float* __restrict__ k,
    const float* __restrict__ v, float* __restrict__ o)
{
    const int qb = blockIdx.x;     // 0..31 (q tile)
    const int bh = blockIdx.y;     // 0..31
    const int b  = bh >> 4;
    const int h  = bh & 15;

    const int tid = threadIdx.x;
    const int tr  = tid >> 4;      // 0..15 -> rows tr*4..tr*4+3
    const int tc  = tid & 15;      // 0..15 -> cols tc*4..tc*4+3

    __shared__ float Qs[64][68];   // stride 68 breaks the 64-float bank alias
    __shared__ float KPs[64][68];  // K tile, then reused for P
    __shared__ float Vs[64][68];

    const size_t base = (size_t)b * SS * DIM + (size_t)h * HD;
    const float* qp = q + base + (size_t)(qb * 64) * DIM;

    // load Q tile (64 x 64)
#pragma unroll
    for (int i = 0; i < 4; i++) {
        int id  = tid + i * 256;       // 0..1023
        int row = id >> 4;             // 0..63
        int c4  = (id & 15) * 4;       // 0..60
        *(float4*)(&Qs[row][c4]) = *(const float4*)(qp + (size_t)row * DIM + c4);
    }

    float m[4], l[4], oa[4][4];
#pragma unroll
    for (int i = 0; i < 4; i++) {
        m[i] = -INFINITY; l[i] = 0.f;
#pragma unroll
        for (int j = 0; j < 4; j++) oa[i][j] = 0.f;
    }

    const float scale = 0.125f;   // 64^-0.5

    for (int jb = 0; jb < 32; jb++) {
        __syncthreads();   // previous iteration's P/V readers done (also covers Q store)
        const float* kp = k + base + (size_t)(jb * 64) * DIM;
        const float* vp = v + base + (size_t)(jb * 64) * DIM;
#pragma unroll
        for (int i = 0; i < 4; i++) {
            int id  = tid + i * 256;
            int row = id >> 4;
            int c4  = (id & 15) * 4;
            *(float4*)(&KPs[row][c4]) = *(const float4*)(kp + (size_t)row * DIM + c4);
            *(float4*)(&Vs[row][c4])  = *(const float4*)(vp + (size_t)row * DIM + c4);
        }
        __syncthreads();

        // S = scale * Q K^T, 4x4 per thread
        float s[4][4];
#pragma unroll
        for (int i = 0; i < 4; i++)
#pragma unroll
            for (int j = 0; j < 4; j++) s[i][j] = 0.f;

#pragma unroll
        for (int d4 = 0; d4 < 16; d4++) {
            float qr[4][4], kr[4][4];
#pragma unroll
            for (int i = 0; i < 4; i++) {
                float4 t = *(const float4*)(&Qs[tr * 4 + i][d4 * 4]);
                qr[i][0] = t.x; qr[i][1] = t.y; qr[i][2] = t.z; qr[i][3] = t.w;
            }
#pragma unroll
            for (int j = 0; j < 4; j++) {
                float4 t = *(const float4*)(&KPs[tc * 4 + j][d4 * 4]);
                kr[j][0] = t.x; kr[j][1] = t.y; kr[j][2] = t.z; kr[j][3] = t.w;
            }
#pragma unroll
            for (int dd = 0; dd < 4; dd++)
#pragma unroll
                for (int i = 0; i < 4; i++)
#pragma unroll
                    for (int j = 0; j < 4; j++)
                        s[i][j] = fmaf(qr[i][dd], kr[j][dd], s[i][j]);
        }
#pragma unroll
        for (int i = 0; i < 4; i++)
#pragma unroll
            for (int j = 0; j < 4; j++) s[i][j] *= scale;

        // row statistics (reduce across the 16 tc lanes, all within one wave)
        float mnew[4], alpha[4], lnew[4], p[4][4];
#pragma unroll
        for (int i = 0; i < 4; i++) {
            float smax = fmaxf(fmaxf(s[i][0], s[i][1]), fmaxf(s[i][2], s[i][3]));
#pragma unroll
            for (int off = 1; off < 16; off <<= 1)
                smax = fmaxf(smax, __shfl_xor(smax, off, 64));
            mnew[i]  = fmaxf(m[i], smax);
            alpha[i] = expf(m[i] - mnew[i]);
            float ps = 0.f;
#pragma unroll
            for (int j = 0; j < 4; j++) {
                p[i][j] = expf(s[i][j] - mnew[i]);
                ps += p[i][j];
            }
#pragma unroll
            for (int off = 1; off < 16; off <<= 1)
                ps += __shfl_xor(ps, off, 64);
            lnew[i] = alpha[i] * l[i] + ps;
        }

        __syncthreads();   // all K reads done -> safe to overwrite with P
#pragma unroll
        for (int i = 0; i < 4; i++)
#pragma unroll
            for (int j = 0; j < 4; j++)
                KPs[tr * 4 + i][tc * 4 + j] = p[i][j];
        __syncthreads();

        // PO = P @ V, 4x4 per thread (rows tr*4+i, d-cols tc*4+j)
        float po[4][4];
#pragma unroll
        for (int i = 0; i < 4; i++)
#pragma unroll
            for (int j = 0; j < 4; j++) po[i][j] = 0.f;

#pragma unroll
        for (int c4 = 0; c4 < 16; c4++) {
            float pr[4][4];
#pragma unroll
            for (int i = 0; i < 4; i++) {
                float4 t = *(const float4*)(&KPs[tr * 4 + i][c4 * 4]);
                pr[i][0] = t.x; pr[i][1] = t.y; pr[i][2] = t.z; pr[i][3] = t.w;
            }
#pragma unroll
            for (int cc = 0; cc < 4; cc++) {
                float4 vv = *(const float4*)(&Vs[c4 * 4 + cc][tc * 4]);
#pragma unroll
                for (int i = 0; i < 4; i++) {
                    po[i][0] = fmaf(pr[i][cc], vv.x, po[i][0]);
                    po[i][1] = fmaf(pr[i][cc], vv.y, po[i][1]);
                    po[i][2] = fmaf(pr[i][cc], vv.z, po[i][2]);
                    po[i][3] = fmaf(pr[i][cc], vv.w, po[i][3]);
                }
            }
        }

        // O = (alpha*O + PO) / l_new   — the reference's per-step division
#pragma unroll
        for (int i = 0; i < 4; i++) {
            float inv = 1.f / lnew[i];
#pragma unroll
            for (int j = 0; j < 4; j++)
                oa[i][j] = (alpha[i] * oa[i][j] + po[i][j]) * inv;
            m[i] = mnew[i];
            l[i] = lnew[i];
        }
    }

    // write O tile to (B,S,H*D)
    float* op = o + base + (size_t)(qb * 64) * DIM;
#pragma unroll
    for (int i = 0; i < 4; i++) {
        int row = tr * 4 + i;
        float4 o4 = make_float4(oa[i][0], oa[i][1], oa[i][2], oa[i][3]);
        *(float4*)(op + (size_t)row * DIM + tc * 4) = o4;
    }
}

// ---------------------------------------------------------------------------
extern "C" void kernel_launch(void* const* d_in, const int* in_sizes, int n_in,
                              void* d_out, int out_size, void* d_ws, size_t ws_size,
                              hipStream_t stream)
{
    const float* x  = (const float*)d_in[0];
    const float* Wq = (const float*)d_in[1];
    const float* Wk = (const float*)d_in[2];
    const float* Wv = (const float*)d_in[3];
    const float* Wo = (const float*)d_in[4];
    float* out = (float*)d_out;

    float* ws = (float*)d_ws;
    float* qw = ws;
    float* kw = ws + (size_t)1 * MTOT * DIM;
    float* vw = ws + (size_t)2 * MTOT * DIM;
    float* ow = ws + (size_t)3 * MTOT * DIM;   // 64 MB total fp32 scratch

    dim3 blk(256);

    // Q/K/V projections (fused over blockIdx.z)
    sgemm3_kernel<<<dim3(8, 32, 3), blk, 0, stream>>>(x, Wq, Wk, Wv, qw, kw, vw);

    // attention (exact reference recurrence, kv block = 64)
    attn_kernel<<<dim3(32, 32), blk, 0, stream>>>(qw, kw, vw, ow);

    // output projection
    sgemm3_kernel<<<dim3(8, 32, 1), blk, 0, stream>>>(ow, Wo, Wo, Wo, out, out, out);
}

// Round 2
// 723.071 us; speedup vs baseline: 1.5950x; 1.5950x over previous
//
#include <hip/hip_runtime.h>
#include <hip/hip_bf16.h>
#include <math.h>

#define BB   2
#define SS   2048
#define DIM  1024
#define NH   16
#define HD   64
#define MTOT (BB * SS)   // 4096

typedef __attribute__((ext_vector_type(8))) short short8v;   // 8 bf16 (4 VGPRs)
typedef __attribute__((ext_vector_type(4))) float float4v;   // 4 fp32 acc

union FragU { short8v v; unsigned short us[8]; unsigned int u[4]; };

__device__ inline unsigned short f2bf(float x) {             // fp32 -> bf16 RNE
    unsigned u = __builtin_bit_cast(unsigned, x);
    u += 0x7fffu + ((u >> 16) & 1u);
    return (unsigned short)(u >> 16);
}
__device__ inline float bf2f(unsigned short h) {
    unsigned u = ((unsigned)h) << 16;
    return __builtin_bit_cast(float, u);
}
__device__ inline void split4(const float4& x, short4& hi, short4& lo) {
    unsigned short h0 = f2bf(x.x), h1 = f2bf(x.y), h2 = f2bf(x.z), h3 = f2bf(x.w);
    hi = make_short4((short)h0, (short)h1, (short)h2, (short)h3);
    lo = make_short4((short)f2bf(x.x - bf2f(h0)), (short)f2bf(x.y - bf2f(h1)),
                     (short)f2bf(x.z - bf2f(h2)), (short)f2bf(x.w - bf2f(h3)));
}
// 64x64 bf16 LDS tile, 16B-group XOR swizzle (row stride 64 -> bank spread)
__device__ inline int kv_off(int row, int d) {
    return row * 64 + ((((d >> 3) ^ (row & 7)) << 3) | (d & 7));
}
// 128x64 u32 LDS tile (packed P hi|lo), 16B-group XOR swizzle
__device__ inline int p_off(int qq, int kv) {
    return qq * 64 + ((((kv >> 2) ^ (qq & 7)) << 2) | (kv & 3));
}

// ---------------------------------------------------------------------------
// SGEMM: Y = X @ W (fp32 vector ALU).  Unchanged from round 1.
// ---------------------------------------------------------------------------
__global__ __launch_bounds__(256) void sgemm3_kernel(
    const float* __restrict__ X,
    const float* __restrict__ W0, const float* __restrict__ W1, const float* __restrict__ W2,
    float* __restrict__ Y0, float* __restrict__ Y1, float* __restrict__ Y2)
{
    const int z = blockIdx.z;
    const float* __restrict__ W = (z == 0) ? W0 : (z == 1) ? W1 : W2;
    float* __restrict__ Y       = (z == 0) ? Y0 : (z == 1) ? Y1 : Y2;

    const int K = 1024, N = 1024;
    const int m0 = blockIdx.y * 128;
    const int n0 = blockIdx.x * 128;
    const int tid = threadIdx.x;
    const int tr = tid >> 4;
    const int tc = tid & 15;

    __shared__ float As[16][132];
    __shared__ float Bs[16][132];

    float acc[8][8];
#pragma unroll
    for (int i = 0; i < 8; i++)
#pragma unroll
        for (int j = 0; j < 8; j++) acc[i][j] = 0.f;

    for (int k0 = 0; k0 < K; k0 += 16) {
#pragma unroll
        for (int i = 0; i < 2; i++) {
            int id  = tid + i * 256;
            int row = id >> 2;
            int c4  = (id & 3) * 4;
            float4 xv = *(const float4*)(X + (size_t)(m0 + row) * K + k0 + c4);
            As[c4 + 0][row] = xv.x;
            As[c4 + 1][row] = xv.y;
            As[c4 + 2][row] = xv.z;
            As[c4 + 3][row] = xv.w;
        }
#pragma unroll
        for (int i = 0; i < 2; i++) {
            int id  = tid + i * 256;
            int row = id >> 5;
            int c4  = (id & 31) * 4;
            *(float4*)(&Bs[row][c4]) = *(const float4*)(W + (size_t)(k0 + row) * N + n0 + c4);
        }
        __syncthreads();

#pragma unroll
        for (int kk = 0; kk < 16; kk++) {
            float4 a0 = *(const float4*)(&As[kk][tr * 4]);
            float4 a1 = *(const float4*)(&As[kk][64 + tr * 4]);
            float4 b0 = *(const float4*)(&Bs[kk][tc * 4]);
            float4 b1 = *(const float4*)(&Bs[kk][64 + tc * 4]);
            float a[8] = {a0.x, a0.y, a0.z, a0.w, a1.x, a1.y, a1.z, a1.w};
            float b[8] = {b0.x, b0.y, b0.z, b0.w, b1.x, b1.y, b1.z, b1.w};
#pragma unroll
            for (int i = 0; i < 8; i++)
#pragma unroll
                for (int j = 0; j < 8; j++)
                    acc[i][j] = fmaf(a[i], b[j], acc[i][j]);
        }
        __syncthreads();
    }

#pragma unroll
    for (int gi = 0; gi < 2; gi++)
#pragma unroll
        for (int i = 0; i < 4; i++) {
            int row = m0 + gi * 64 + tr * 4 + i;
#pragma unroll
            for (int gj = 0; gj < 2; gj++) {
                float4 o4 = make_float4(acc[gi * 4 + i][gj * 4 + 0],
                                        acc[gi * 4 + i][gj * 4 + 1],
                                        acc[gi * 4 + i][gj * 4 + 2],
                                        acc[gi * 4 + i][gj * 4 + 3]);
                *(float4*)(Y + (size_t)row * N + n0 + gj * 64 + tc * 4) = o4;
            }
        }
}

// ---------------------------------------------------------------------------
// MFMA attention, split-bf16 (hi+lo) emulated fp32, exact reference recurrence:
//   m_new = max(m, rowmax(S)); alpha = exp(m-m_new); P = exp(S-m_new)
//   l_new = alpha*l + rowsum(P);  O = (alpha*O + P@V)/l_new   every kv step.
// Block: 4 waves x 32 q-rows = 128 q rows. kv block = 64 (semantic).
// Wave-private tiles: S/P rows; shared LDS: K (row-major), V (transposed),
// P (packed hi|lo u32). MFMA 16x16x32_bf16: A[m=lane&15][k=quad*8+j],
// B[k=quad*8+j][n=lane&15], C row=quad*4+reg, col=lane&15 (m89-verified).
// rowsum(P) via ones-column MFMA (lands in matching C rows per lane).
// ---------------------------------------------------------------------------
__global__ __launch_bounds__(256, 2) void attn_mfma_kernel(
    const float* __restrict__ q, const float* __restrict__ k,
    const float* __restrict__ v, float* __restrict__ o)
{
    __shared__ __align__(16) unsigned short KhS[64 * 64];
    __shared__ __align__(16) unsigned short KlS[64 * 64];
    __shared__ __align__(16) unsigned short VhS[64 * 64];   // transposed: [d][kv]
    __shared__ __align__(16) unsigned short VlS[64 * 64];
    __shared__ __align__(16) unsigned int   PpS[128 * 64];  // hi | lo<<16

    const int tid  = threadIdx.x;
    const int wave = tid >> 6, lane = tid & 63;
    const int quad = lane >> 4, l15 = lane & 15;
    const int bh = blockIdx.y, b = bh >> 4, h = bh & 15;
    const size_t base = (size_t)b * SS * DIM + (size_t)h * HD;
    const int qs0 = blockIdx.x * 128 + wave * 32;   // this wave's q-row base

    // ---- preload Q fragments (x 1/8 scale folded in exactly; bf16 split) ----
    FragU Qh[2][2], Ql[2][2];
#pragma unroll
    for (int rt = 0; rt < 2; rt++) {
        const int qrow = qs0 + rt * 16 + l15;
#pragma unroll
        for (int ks = 0; ks < 2; ks++) {
            const float* p0 = q + base + (size_t)qrow * DIM + ks * 32 + quad * 8;
            float4 a = *(const float4*)(p0);
            float4 c = *(const float4*)(p0 + 4);
            float e[8] = {a.x, a.y, a.z, a.w, c.x, c.y, c.z, c.w};
#pragma unroll
            for (int j = 0; j < 8; j++) {
                float x = e[j] * 0.125f;
                unsigned short hs = f2bf(x);
                Qh[rt][ks].us[j] = hs;
                Ql[rt][ks].us[j] = f2bf(x - bf2f(hs));
            }
        }
    }

    FragU onesF;
#pragma unroll
    for (int i = 0; i < 4; i++) onesF.u[i] = 0x3F803F80u;   // bf16 1.0 pairs

    float4v Oacc[2][4];
#pragma unroll
    for (int rt = 0; rt < 2; rt++)
#pragma unroll
        for (int dt = 0; dt < 4; dt++) Oacc[rt][dt] = (float4v){0.f, 0.f, 0.f, 0.f};

    float m_run[2][4], l_run[2][4];
#pragma unroll
    for (int rt = 0; rt < 2; rt++)
#pragma unroll
        for (int r = 0; r < 4; r++) { m_run[rt][r] = -INFINITY; l_run[rt][r] = 0.f; }

    for (int jb = 0; jb < 32; jb++) {
        __syncthreads();   // prev iter's K/V readers done
        // ---- stage K: row-major [kv][d], bf16 hi/lo, swizzled, b64 writes ----
        {
            const float* kp = k + base + (size_t)(jb * 64) * DIM;
            const int d4 = (tid & 15) * 4;
#pragma unroll
            for (int i = 0; i < 4; i++) {
                const int kvr = (tid >> 4) + 16 * i;
                float4 x = *(const float4*)(kp + (size_t)kvr * DIM + d4);
                short4 hi, lo; split4(x, hi, lo);
                *(short4*)(&KhS[kv_off(kvr, d4)]) = hi;
                *(short4*)(&KlS[kv_off(kvr, d4)]) = lo;
            }
        }
        // ---- stage V transposed [d][kv] via in-register 4x4 transpose ----
        {
            const float* vp = v + base + (size_t)(jb * 64) * DIM;
            const int kv4 = (tid >> 4) * 4;
            const int d4  = (tid & 15) * 4;
            float cr[4][4];
#pragma unroll
            for (int r = 0; r < 4; r++) {
                float4 t = *(const float4*)(vp + (size_t)(kv4 + r) * DIM + d4);
                cr[r][0] = t.x; cr[r][1] = t.y; cr[r][2] = t.z; cr[r][3] = t.w;
            }
#pragma unroll
            for (int c = 0; c < 4; c++) {
                float4 colv = make_float4(cr[0][c], cr[1][c], cr[2][c], cr[3][c]);
                short4 hi, lo; split4(colv, hi, lo);
                *(short4*)(&VhS[kv_off(d4 + c, kv4)]) = hi;
                *(short4*)(&VlS[kv_off(d4 + c, kv4)]) = lo;
            }
        }
        __syncthreads();

        // ---- S = (Q/8) @ K^T : 3 split passes ----
        float4v s[2][4];
#pragma unroll
        for (int rt = 0; rt < 2; rt++)
#pragma unroll
            for (int ct = 0; ct < 4; ct++) s[rt][ct] = (float4v){0.f, 0.f, 0.f, 0.f};

#pragma unroll
        for (int ks = 0; ks < 2; ks++) {
            FragU khf[4], klf[4];
#pragma unroll
            for (int ct = 0; ct < 4; ct++) {
                khf[ct].v = *(const short8v*)(&KhS[kv_off(ct * 16 + l15, ks * 32 + quad * 8)]);
                klf[ct].v = *(const short8v*)(&KlS[kv_off(ct * 16 + l15, ks * 32 + quad * 8)]);
            }
#pragma unroll
            for (int rt = 0; rt < 2; rt++)
#pragma unroll
                for (int ct = 0; ct < 4; ct++) {
                    s[rt][ct] = __builtin_amdgcn_mfma_f32_16x16x32_bf16(Qh[rt][ks].v, khf[ct].v, s[rt][ct], 0, 0, 0);
                    s[rt][ct] = __builtin_amdgcn_mfma_f32_16x16x32_bf16(Qh[rt][ks].v, klf[ct].v, s[rt][ct], 0, 0, 0);
                    s[rt][ct] = __builtin_amdgcn_mfma_f32_16x16x32_bf16(Ql[rt][ks].v, khf[ct].v, s[rt][ct], 0, 0, 0);
                }
        }

        // ---- row stats: exact fp32 running max (semantically required) ----
        float mn[2][4], al[2][4];
#pragma unroll
        for (int rt = 0; rt < 2; rt++)
#pragma unroll
            for (int r = 0; r < 4; r++) {
                float v0 = fmaxf(fmaxf(s[rt][0][r], s[rt][1][r]),
                                 fmaxf(s[rt][2][r], s[rt][3][r]));
#pragma unroll
                for (int msk = 1; msk < 16; msk <<= 1)
                    v0 = fmaxf(v0, __shfl_xor(v0, msk, 64));
                float mm = fmaxf(m_run[rt][r], v0);
                mn[rt][r] = mm;
                al[rt][r] = __expf(m_run[rt][r] - mm);   // exp(-inf)=0 on 1st iter
            }

        // ---- P = exp(S - mn), split hi/lo, packed u32 -> LDS (wave-local rows) ----
#pragma unroll
        for (int rt = 0; rt < 2; rt++)
#pragma unroll
            for (int ct = 0; ct < 4; ct++)
#pragma unroll
                for (int r = 0; r < 4; r++) {
                    float p = __expf(s[rt][ct][r] - mn[rt][r]);
                    unsigned short hs = f2bf(p);
                    unsigned short ls = f2bf(p - bf2f(hs));
                    PpS[p_off(wave * 32 + rt * 16 + quad * 4 + r, ct * 16 + l15)] =
                        (unsigned)hs | ((unsigned)ls << 16);
                }
        __syncthreads();

        // ---- reload P as A-operand fragments ----
        FragU PhF[2][2], PlF[2][2];
#pragma unroll
        for (int rt = 0; rt < 2; rt++)
#pragma unroll
            for (int ks = 0; ks < 2; ks++) {
                const int qrow = wave * 32 + rt * 16 + l15;
                const int kv0  = ks * 32 + quad * 8;
                uint4 r0 = *(const uint4*)(&PpS[p_off(qrow, kv0)]);
                uint4 r1 = *(const uint4*)(&PpS[p_off(qrow, kv0 + 4)]);
                unsigned w[8] = {r0.x, r0.y, r0.z, r0.w, r1.x, r1.y, r1.z, r1.w};
#pragma unroll
                for (int t2 = 0; t2 < 4; t2++) {
                    unsigned x0 = w[2 * t2], x1 = w[2 * t2 + 1];
                    PhF[rt][ks].u[t2] = (x0 & 0xffffu) | (x1 << 16);
                    PlF[rt][ks].u[t2] = (x0 >> 16) | (x1 & 0xffff0000u);
                }
            }

        // ---- rowsum(P) via ones-column MFMA (exact fp32 sum of split P) ----
        float4v co[2];
        co[0] = (float4v){0.f, 0.f, 0.f, 0.f};
        co[1] = (float4v){0.f, 0.f, 0.f, 0.f};
#pragma unroll
        for (int rt = 0; rt < 2; rt++)
#pragma unroll
            for (int ks = 0; ks < 2; ks++) {
                co[rt] = __builtin_amdgcn_mfma_f32_16x16x32_bf16(PhF[rt][ks].v, onesF.v, co[rt], 0, 0, 0);
                co[rt] = __builtin_amdgcn_mfma_f32_16x16x32_bf16(PlF[rt][ks].v, onesF.v, co[rt], 0, 0, 0);
            }

        float ln[2][4];
#pragma unroll
        for (int rt = 0; rt < 2; rt++)
#pragma unroll
            for (int r = 0; r < 4; r++)
                ln[rt][r] = al[rt][r] * l_run[rt][r] + co[rt][r];

        // ---- O = alpha*O, then += P@V via MFMA ----
#pragma unroll
        for (int rt = 0; rt < 2; rt++)
#pragma unroll
            for (int dt = 0; dt < 4; dt++)
#pragma unroll
                for (int r = 0; r < 4; r++)
                    Oacc[rt][dt][r] *= al[rt][r];

#pragma unroll
        for (int ks = 0; ks < 2; ks++)
#pragma unroll
            for (int dt = 0; dt < 4; dt++) {
                FragU vhf, vlf;
                vhf.v = *(const short8v*)(&VhS[kv_off(dt * 16 + l15, ks * 32 + quad * 8)]);
                vlf.v = *(const short8v*)(&VlS[kv_off(dt * 16 + l15, ks * 32 + quad * 8)]);
#pragma unroll
                for (int rt = 0; rt < 2; rt++) {
                    Oacc[rt][dt] = __builtin_amdgcn_mfma_f32_16x16x32_bf16(PhF[rt][ks].v, vhf.v, Oacc[rt][dt], 0, 0, 0);
                    Oacc[rt][dt] = __builtin_amdgcn_mfma_f32_16x16x32_bf16(PhF[rt][ks].v, vlf.v, Oacc[rt][dt], 0, 0, 0);
                    Oacc[rt][dt] = __builtin_amdgcn_mfma_f32_16x16x32_bf16(PlF[rt][ks].v, vhf.v, Oacc[rt][dt], 0, 0, 0);
                }
            }

        // ---- O /= l_new (reference divides every step) ----
#pragma unroll
        for (int rt = 0; rt < 2; rt++)
#pragma unroll
            for (int r = 0; r < 4; r++) {
                float inv = 1.0f / ln[rt][r];
#pragma unroll
                for (int dt = 0; dt < 4; dt++)
                    Oacc[rt][dt][r] *= inv;
                m_run[rt][r] = mn[rt][r];
                l_run[rt][r] = ln[rt][r];
            }
    }

    // ---- store O (fp32, (B,S,H*D) layout) ----
#pragma unroll
    for (int rt = 0; rt < 2; rt++)
#pragma unroll
        for (int r = 0; r < 4; r++) {
            const int row = qs0 + rt * 16 + quad * 4 + r;
            float* op = o + base + (size_t)row * DIM;
#pragma unroll
            for (int dt = 0; dt < 4; dt++)
                op[dt * 16 + l15] = Oacc[rt][dt][r];
        }
}

// ---------------------------------------------------------------------------
extern "C" void kernel_launch(void* const* d_in, const int* in_sizes, int n_in,
                              void* d_out, int out_size, void* d_ws, size_t ws_size,
                              hipStream_t stream)
{
    const float* x  = (const float*)d_in[0];
    const float* Wq = (const float*)d_in[1];
    const float* Wk = (const float*)d_in[2];
    const float* Wv = (const float*)d_in[3];
    const float* Wo = (const float*)d_in[4];
    float* out = (float*)d_out;

    float* ws = (float*)d_ws;
    float* qw = ws;
    float* kw = ws + (size_t)1 * MTOT * DIM;
    float* vw = ws + (size_t)2 * MTOT * DIM;
    float* ow = ws + (size_t)3 * MTOT * DIM;

    dim3 blk(256);

    // Q/K/V projections (fp32 vector GEMM, fused over blockIdx.z)
    sgemm3_kernel<<<dim3(8, 32, 3), blk, 0, stream>>>(x, Wq, Wk, Wv, qw, kw, vw);

    // attention (split-bf16 MFMA, exact reference recurrence, kv block = 64)
    attn_mfma_kernel<<<dim3(16, 32), blk, 0, stream>>>(qw, kw, vw, ow);

    // output projection
    sgemm3_kernel<<<dim3(8, 32, 1), blk, 0, stream>>>(ow, Wo, Wo, Wo, out, out, out);
}

// Round 3
// 418.794 us; speedup vs baseline: 2.7538x; 1.7266x over previous
//
#include <hip/hip_runtime.h>
#include <hip/hip_bf16.h>
#include <math.h>

#define BB   2
#define SS   2048
#define DIM  1024
#define NH   16
#define HD   64
#define MTOT (BB * SS)   // 4096

typedef unsigned short ushortT;
typedef __attribute__((ext_vector_type(8))) short short8v;   // 8 bf16 (4 VGPRs)
typedef __attribute__((ext_vector_type(4))) float float4v;   // 4 fp32 acc

union FragU { short8v v; unsigned short us[8]; unsigned int u[4]; };

__device__ inline unsigned short f2bf(float x) {             // fp32 -> bf16 RNE
    unsigned u = __builtin_bit_cast(unsigned, x);
    u += 0x7fffu + ((u >> 16) & 1u);
    return (unsigned short)(u >> 16);
}
__device__ inline float bf2f(unsigned short h) {
    unsigned u = ((unsigned)h) << 16;
    return __builtin_bit_cast(float, u);
}
__device__ inline void split4(const float4& x, short4& hi, short4& lo) {
    unsigned short h0 = f2bf(x.x), h1 = f2bf(x.y), h2 = f2bf(x.z), h3 = f2bf(x.w);
    hi = make_short4((short)h0, (short)h1, (short)h2, (short)h3);
    lo = make_short4((short)f2bf(x.x - bf2f(h0)), (short)f2bf(x.y - bf2f(h1)),
                     (short)f2bf(x.z - bf2f(h2)), (short)f2bf(x.w - bf2f(h3)));
}
// async global->LDS, 16 B per lane (dest = wave-uniform base + lane*16)
__device__ inline void gld_lds16(const void* g, void* l) {
    __builtin_amdgcn_global_load_lds(
        (const __attribute__((address_space(1))) void*)g,
        (__attribute__((address_space(3))) void*)l, 16, 0, 0);
}
// 64x64 bf16 LDS tile swizzle for the attention kernel (unchanged)
__device__ inline int kv_off(int row, int d) {
    return row * 64 + ((((d >> 3) ^ (row & 7)) << 3) | (d & 7));
}
__device__ inline int p_off(int qq, int kv) {
    return qq * 64 + ((((kv >> 2) ^ (qq & 7)) << 2) | (kv & 3));
}

// ---------------------------------------------------------------------------
// fp32 -> bf16 hi/lo elementwise split (X and attention-O)
// ---------------------------------------------------------------------------
__global__ __launch_bounds__(256) void convert_split_kernel(
    const float* __restrict__ in, ushortT* __restrict__ hi, ushortT* __restrict__ lo, int n4)
{
    int t = blockIdx.x * 256 + threadIdx.x;
    if (t < n4) {
        float4 x = ((const float4*)in)[t];
        short4 h, l; split4(x, h, l);
        ((short4*)hi)[t] = h;
        ((short4*)lo)[t] = l;
    }
}

// ---------------------------------------------------------------------------
// W (1024x1024 fp32, K-major) -> W^T (1024x1024 bf16 hi/lo, N-major rows of K)
// blockIdx.z selects which W; outputs stacked [z][1024][1024].
// ---------------------------------------------------------------------------
__global__ __launch_bounds__(256) void transpose_split_kernel(
    const float* __restrict__ W0, const float* __restrict__ W1,
    const float* __restrict__ W2, const float* __restrict__ W3,
    ushortT* __restrict__ WtH, ushortT* __restrict__ WtL)
{
    const int z = blockIdx.z;
    const float* __restrict__ W = (z == 0) ? W0 : (z == 1) ? W1 : (z == 2) ? W2 : W3;
    ushortT* H = WtH + (size_t)z * 1024 * 1024;
    ushortT* L = WtL + (size_t)z * 1024 * 1024;

    __shared__ float T[64][65];
    const int k0 = blockIdx.y * 64, n0 = blockIdx.x * 64;
    const int tid = threadIdx.x;
    const int c4 = (tid & 15) * 4;

#pragma unroll
    for (int i = 0; i < 4; i++) {
        int r = (tid >> 4) + 16 * i;
        *(float4*)&T[r][c4] = *(const float4*)(W + (size_t)(k0 + r) * 1024 + n0 + c4);
    }
    __syncthreads();
#pragma unroll
    for (int i = 0; i < 4; i++) {
        int n = (tid >> 4) + 16 * i;
        float4 vv = make_float4(T[c4 + 0][n], T[c4 + 1][n], T[c4 + 2][n], T[c4 + 3][n]);
        short4 h, l; split4(vv, h, l);
        *(short4*)&H[(size_t)(n0 + n) * 1024 + k0 + c4] = h;
        *(short4*)&L[(size_t)(n0 + n) * 1024 + k0 + c4] = l;
    }
}

// ---------------------------------------------------------------------------
// Split-bf16 MFMA GEMM: Y(MxN fp32) = A(MxK) @ Bt(NxK)^T, 3 passes
// (Ah*Bh + Ah*Bl + Al*Bh). 128x128 tile, BK=32, 4 waves (2x2 of 64x64).
// m97 structure: global_load_lds width-16 staging, 2-barrier K-loop.
// blockIdx.z selects Bt slice (z*1024*1024) and output Y.
// ---------------------------------------------------------------------------
__global__ __launch_bounds__(256, 2) void gemm_bt_split_kernel(
    const ushortT* __restrict__ Ah, const ushortT* __restrict__ Al,
    const ushortT* __restrict__ BtH, const ushortT* __restrict__ BtL,
    float* __restrict__ Y0, float* __restrict__ Y1, float* __restrict__ Y2)
{
    const int z = blockIdx.z;
    const ushortT* __restrict__ Bh = BtH + (size_t)z * 1024 * 1024;
    const ushortT* __restrict__ Bl = BtL + (size_t)z * 1024 * 1024;
    float* __restrict__ Y = (z == 0) ? Y0 : (z == 1) ? Y1 : Y2;

    const int K = 1024, N = 1024;
    const int m0 = blockIdx.y * 128;
    const int n0 = blockIdx.x * 128;

    __shared__ __align__(16) ushortT AhS[128 * 32];
    __shared__ __align__(16) ushortT AlS[128 * 32];
    __shared__ __align__(16) ushortT BhS[128 * 32];
    __shared__ __align__(16) ushortT BlS[128 * 32];

    const int tid  = threadIdx.x;
    const int wave = tid >> 6, lane = tid & 63;
    const int quad = lane >> 4, l15 = lane & 15;
    const int wm = wave >> 1, wn = wave & 1;

    // staging slots: slot s (0..511) -> row s>>2, 16B-group s&3
    const int s0 = tid, s1 = tid + 256;
    const int ar0 = s0 >> 2, ak0 = (s0 & 3) * 8;
    const int ar1 = s1 >> 2, ak1 = (s1 & 3) * 8;

    float4v acc[4][4];
#pragma unroll
    for (int i = 0; i < 4; i++)
#pragma unroll
        for (int j = 0; j < 4; j++) acc[i][j] = (float4v){0.f, 0.f, 0.f, 0.f};

    for (int k0 = 0; k0 < K; k0 += 32) {
        __syncthreads();
        gld_lds16(Ah + (size_t)(m0 + ar0) * K + k0 + ak0, &AhS[s0 * 8]);
        gld_lds16(Ah + (size_t)(m0 + ar1) * K + k0 + ak1, &AhS[s1 * 8]);
        gld_lds16(Al + (size_t)(m0 + ar0) * K + k0 + ak0, &AlS[s0 * 8]);
        gld_lds16(Al + (size_t)(m0 + ar1) * K + k0 + ak1, &AlS[s1 * 8]);
        gld_lds16(Bh + (size_t)(n0 + ar0) * K + k0 + ak0, &BhS[s0 * 8]);
        gld_lds16(Bh + (size_t)(n0 + ar1) * K + k0 + ak1, &BhS[s1 * 8]);
        gld_lds16(Bl + (size_t)(n0 + ar0) * K + k0 + ak0, &BlS[s0 * 8]);
        gld_lds16(Bl + (size_t)(n0 + ar1) * K + k0 + ak1, &BlS[s1 * 8]);
        __syncthreads();   // drains vmcnt (global_load_lds) + lgkm

        FragU ah[4], al[4], bh[4], bl[4];
#pragma unroll
        for (int t = 0; t < 4; t++) {
            ah[t].v = *(const short8v*)&AhS[(wm * 64 + t * 16 + l15) * 32 + quad * 8];
            al[t].v = *(const short8v*)&AlS[(wm * 64 + t * 16 + l15) * 32 + quad * 8];
            bh[t].v = *(const short8v*)&BhS[(wn * 64 + t * 16 + l15) * 32 + quad * 8];
            bl[t].v = *(const short8v*)&BlS[(wn * 64 + t * 16 + l15) * 32 + quad * 8];
        }
#pragma unroll
        for (int mt = 0; mt < 4; mt++)
#pragma unroll
            for (int nt = 0; nt < 4; nt++) {
                acc[mt][nt] = __builtin_amdgcn_mfma_f32_16x16x32_bf16(ah[mt].v, bh[nt].v, acc[mt][nt], 0, 0, 0);
                acc[mt][nt] = __builtin_amdgcn_mfma_f32_16x16x32_bf16(ah[mt].v, bl[nt].v, acc[mt][nt], 0, 0, 0);
                acc[mt][nt] = __builtin_amdgcn_mfma_f32_16x16x32_bf16(al[mt].v, bh[nt].v, acc[mt][nt], 0, 0, 0);
            }
    }

    // epilogue: C row = quad*4+reg, col = lane&15 (m89-verified)
#pragma unroll
    for (int mt = 0; mt < 4; mt++)
#pragma unroll
        for (int r = 0; r < 4; r++) {
            const int row = m0 + wm * 64 + mt * 16 + quad * 4 + r;
            float* yp = Y + (size_t)row * N + n0 + wn * 64 + l15;
#pragma unroll
            for (int nt = 0; nt < 4; nt++)
                yp[nt * 16] = acc[mt][nt][r];
        }
}

// ---------------------------------------------------------------------------
// MFMA attention (unchanged from round 2): split-bf16, exact reference
// recurrence with per-step division.
// ---------------------------------------------------------------------------
__global__ __launch_bounds__(256, 2) void attn_mfma_kernel(
    const float* __restrict__ q, const float* __restrict__ k,
    const float* __restrict__ v, float* __restrict__ o)
{
    __shared__ __align__(16) unsigned short KhS[64 * 64];
    __shared__ __align__(16) unsigned short KlS[64 * 64];
    __shared__ __align__(16) unsigned short VhS[64 * 64];   // transposed: [d][kv]
    __shared__ __align__(16) unsigned short VlS[64 * 64];
    __shared__ __align__(16) unsigned int   PpS[128 * 64];  // hi | lo<<16

    const int tid  = threadIdx.x;
    const int wave = tid >> 6, lane = tid & 63;
    const int quad = lane >> 4, l15 = lane & 15;
    const int bh = blockIdx.y, b = bh >> 4, h = bh & 15;
    const size_t base = (size_t)b * SS * DIM + (size_t)h * HD;
    const int qs0 = blockIdx.x * 128 + wave * 32;

    FragU Qh[2][2], Ql[2][2];
#pragma unroll
    for (int rt = 0; rt < 2; rt++) {
        const int qrow = qs0 + rt * 16 + l15;
#pragma unroll
        for (int ks = 0; ks < 2; ks++) {
            const float* p0 = q + base + (size_t)qrow * DIM + ks * 32 + quad * 8;
            float4 a = *(const float4*)(p0);
            float4 c = *(const float4*)(p0 + 4);
            float e[8] = {a.x, a.y, a.z, a.w, c.x, c.y, c.z, c.w};
#pragma unroll
            for (int j = 0; j < 8; j++) {
                float x = e[j] * 0.125f;
                unsigned short hs = f2bf(x);
                Qh[rt][ks].us[j] = hs;
                Ql[rt][ks].us[j] = f2bf(x - bf2f(hs));
            }
        }
    }

    FragU onesF;
#pragma unroll
    for (int i = 0; i < 4; i++) onesF.u[i] = 0x3F803F80u;

    float4v Oacc[2][4];
#pragma unroll
    for (int rt = 0; rt < 2; rt++)
#pragma unroll
        for (int dt = 0; dt < 4; dt++) Oacc[rt][dt] = (float4v){0.f, 0.f, 0.f, 0.f};

    float m_run[2][4], l_run[2][4];
#pragma unroll
    for (int rt = 0; rt < 2; rt++)
#pragma unroll
        for (int r = 0; r < 4; r++) { m_run[rt][r] = -INFINITY; l_run[rt][r] = 0.f; }

    for (int jb = 0; jb < 32; jb++) {
        __syncthreads();
        {
            const float* kp = k + base + (size_t)(jb * 64) * DIM;
            const int d4 = (tid & 15) * 4;
#pragma unroll
            for (int i = 0; i < 4; i++) {
                const int kvr = (tid >> 4) + 16 * i;
                float4 x = *(const float4*)(kp + (size_t)kvr * DIM + d4);
                short4 hi, lo; split4(x, hi, lo);
                *(short4*)(&KhS[kv_off(kvr, d4)]) = hi;
                *(short4*)(&KlS[kv_off(kvr, d4)]) = lo;
            }
        }
        {
            const float* vp = v + base + (size_t)(jb * 64) * DIM;
            const int kv4 = (tid >> 4) * 4;
            const int d4  = (tid & 15) * 4;
            float cr[4][4];
#pragma unroll
            for (int r = 0; r < 4; r++) {
                float4 t = *(const float4*)(vp + (size_t)(kv4 + r) * DIM + d4);
                cr[r][0] = t.x; cr[r][1] = t.y; cr[r][2] = t.z; cr[r][3] = t.w;
            }
#pragma unroll
            for (int c = 0; c < 4; c++) {
                float4 colv = make_float4(cr[0][c], cr[1][c], cr[2][c], cr[3][c]);
                short4 hi, lo; split4(colv, hi, lo);
                *(short4*)(&VhS[kv_off(d4 + c, kv4)]) = hi;
                *(short4*)(&VlS[kv_off(d4 + c, kv4)]) = lo;
            }
        }
        __syncthreads();

        float4v s[2][4];
#pragma unroll
        for (int rt = 0; rt < 2; rt++)
#pragma unroll
            for (int ct = 0; ct < 4; ct++) s[rt][ct] = (float4v){0.f, 0.f, 0.f, 0.f};

#pragma unroll
        for (int ks = 0; ks < 2; ks++) {
            FragU khf[4], klf[4];
#pragma unroll
            for (int ct = 0; ct < 4; ct++) {
                khf[ct].v = *(const short8v*)(&KhS[kv_off(ct * 16 + l15, ks * 32 + quad * 8)]);
                klf[ct].v = *(const short8v*)(&KlS[kv_off(ct * 16 + l15, ks * 32 + quad * 8)]);
            }
#pragma unroll
            for (int rt = 0; rt < 2; rt++)
#pragma unroll
                for (int ct = 0; ct < 4; ct++) {
                    s[rt][ct] = __builtin_amdgcn_mfma_f32_16x16x32_bf16(Qh[rt][ks].v, khf[ct].v, s[rt][ct], 0, 0, 0);
                    s[rt][ct] = __builtin_amdgcn_mfma_f32_16x16x32_bf16(Qh[rt][ks].v, klf[ct].v, s[rt][ct], 0, 0, 0);
                    s[rt][ct] = __builtin_amdgcn_mfma_f32_16x16x32_bf16(Ql[rt][ks].v, khf[ct].v, s[rt][ct], 0, 0, 0);
                }
        }

        float mn[2][4], al[2][4];
#pragma unroll
        for (int rt = 0; rt < 2; rt++)
#pragma unroll
            for (int r = 0; r < 4; r++) {
                float v0 = fmaxf(fmaxf(s[rt][0][r], s[rt][1][r]),
                                 fmaxf(s[rt][2][r], s[rt][3][r]));
#pragma unroll
                for (int msk = 1; msk < 16; msk <<= 1)
                    v0 = fmaxf(v0, __shfl_xor(v0, msk, 64));
                float mm = fmaxf(m_run[rt][r], v0);
                mn[rt][r] = mm;
                al[rt][r] = __expf(m_run[rt][r] - mm);
            }

#pragma unroll
        for (int rt = 0; rt < 2; rt++)
#pragma unroll
            for (int ct = 0; ct < 4; ct++)
#pragma unroll
                for (int r = 0; r < 4; r++) {
                    float p = __expf(s[rt][ct][r] - mn[rt][r]);
                    unsigned short hs = f2bf(p);
                    unsigned short ls = f2bf(p - bf2f(hs));
                    PpS[p_off(wave * 32 + rt * 16 + quad * 4 + r, ct * 16 + l15)] =
                        (unsigned)hs | ((unsigned)ls << 16);
                }
        __syncthreads();

        FragU PhF[2][2], PlF[2][2];
#pragma unroll
        for (int rt = 0; rt < 2; rt++)
#pragma unroll
            for (int ks = 0; ks < 2; ks++) {
                const int qrow = wave * 32 + rt * 16 + l15;
                const int kv0  = ks * 32 + quad * 8;
                uint4 r0 = *(const uint4*)(&PpS[p_off(qrow, kv0)]);
                uint4 r1 = *(const uint4*)(&PpS[p_off(qrow, kv0 + 4)]);
                unsigned w[8] = {r0.x, r0.y, r0.z, r0.w, r1.x, r1.y, r1.z, r1.w};
#pragma unroll
                for (int t2 = 0; t2 < 4; t2++) {
                    unsigned x0 = w[2 * t2], x1 = w[2 * t2 + 1];
                    PhF[rt][ks].u[t2] = (x0 & 0xffffu) | (x1 << 16);
                    PlF[rt][ks].u[t2] = (x0 >> 16) | (x1 & 0xffff0000u);
                }
            }

        float4v co[2];
        co[0] = (float4v){0.f, 0.f, 0.f, 0.f};
        co[1] = (float4v){0.f, 0.f, 0.f, 0.f};
#pragma unroll
        for (int rt = 0; rt < 2; rt++)
#pragma unroll
            for (int ks = 0; ks < 2; ks++) {
                co[rt] = __builtin_amdgcn_mfma_f32_16x16x32_bf16(PhF[rt][ks].v, onesF.v, co[rt], 0, 0, 0);
                co[rt] = __builtin_amdgcn_mfma_f32_16x16x32_bf16(PlF[rt][ks].v, onesF.v, co[rt], 0, 0, 0);
            }

        float ln[2][4];
#pragma unroll
        for (int rt = 0; rt < 2; rt++)
#pragma unroll
            for (int r = 0; r < 4; r++)
                ln[rt][r] = al[rt][r] * l_run[rt][r] + co[rt][r];

#pragma unroll
        for (int rt = 0; rt < 2; rt++)
#pragma unroll
            for (int dt = 0; dt < 4; dt++)
#pragma unroll
                for (int r = 0; r < 4; r++)
                    Oacc[rt][dt][r] *= al[rt][r];

#pragma unroll
        for (int ks = 0; ks < 2; ks++)
#pragma unroll
            for (int dt = 0; dt < 4; dt++) {
                FragU vhf, vlf;
                vhf.v = *(const short8v*)(&VhS[kv_off(dt * 16 + l15, ks * 32 + quad * 8)]);
                vlf.v = *(const short8v*)(&VlS[kv_off(dt * 16 + l15, ks * 32 + quad * 8)]);
#pragma unroll
                for (int rt = 0; rt < 2; rt++) {
                    Oacc[rt][dt] = __builtin_amdgcn_mfma_f32_16x16x32_bf16(PhF[rt][ks].v, vhf.v, Oacc[rt][dt], 0, 0, 0);
                    Oacc[rt][dt] = __builtin_amdgcn_mfma_f32_16x16x32_bf16(PhF[rt][ks].v, vlf.v, Oacc[rt][dt], 0, 0, 0);
                    Oacc[rt][dt] = __builtin_amdgcn_mfma_f32_16x16x32_bf16(PlF[rt][ks].v, vhf.v, Oacc[rt][dt], 0, 0, 0);
                }
            }

#pragma unroll
        for (int rt = 0; rt < 2; rt++)
#pragma unroll
            for (int r = 0; r < 4; r++) {
                float inv = 1.0f / ln[rt][r];
#pragma unroll
                for (int dt = 0; dt < 4; dt++)
                    Oacc[rt][dt][r] *= inv;
                m_run[rt][r] = mn[rt][r];
                l_run[rt][r] = ln[rt][r];
            }
    }

#pragma unroll
    for (int rt = 0; rt < 2; rt++)
#pragma unroll
        for (int r = 0; r < 4; r++) {
            const int row = qs0 + rt * 16 + quad * 4 + r;
            float* op = o + base + (size_t)row * DIM;
#pragma unroll
            for (int dt = 0; dt < 4; dt++)
                op[dt * 16 + l15] = Oacc[rt][dt][r];
        }
}

// ---------------------------------------------------------------------------
extern "C" void kernel_launch(void* const* d_in, const int* in_sizes, int n_in,
                              void* d_out, int out_size, void* d_ws, size_t ws_size,
                              hipStream_t stream)
{
    const float* x  = (const float*)d_in[0];
    const float* Wq = (const float*)d_in[1];
    const float* Wk = (const float*)d_in[2];
    const float* Wv = (const float*)d_in[3];
    const float* Wo = (const float*)d_in[4];
    float* out = (float*)d_out;

    char* w = (char*)d_ws;
    float*   qw  = (float*)(w);                       // 16 MB (reused for Oh/Ol later)
    float*   kw  = (float*)(w + ((size_t)16 << 20));  // 16 MB
    float*   vw  = (float*)(w + ((size_t)32 << 20));  // 16 MB
    float*   ow  = (float*)(w + ((size_t)48 << 20));  // 16 MB
    ushortT* XhS = (ushortT*)(w + ((size_t)64 << 20)); // 8 MB
    ushortT* XlS = (ushortT*)(w + ((size_t)72 << 20)); // 8 MB
    ushortT* WtH = (ushortT*)(w + ((size_t)80 << 20)); // 8 MB (4 matrices)
    ushortT* WtL = (ushortT*)(w + ((size_t)88 << 20)); // 8 MB  -> 96 MB total
    ushortT* OhS = (ushortT*)qw;                       // reuse dead qw
    ushortT* OlS = (ushortT*)(w + ((size_t)8 << 20));

    dim3 blk(256);
    const int n4 = MTOT * DIM / 4;   // 1M float4 groups

    // split X -> bf16 hi/lo
    convert_split_kernel<<<dim3(n4 / 256), blk, 0, stream>>>(x, XhS, XlS, n4);
    // transpose+split all four W
    transpose_split_kernel<<<dim3(16, 16, 4), blk, 0, stream>>>(Wq, Wk, Wv, Wo, WtH, WtL);

    // Q/K/V projections: split-bf16 MFMA GEMM (z = 0,1,2)
    gemm_bt_split_kernel<<<dim3(8, 32, 3), blk, 0, stream>>>(XhS, XlS, WtH, WtL, qw, kw, vw);

    // attention (exact reference recurrence, kv block = 64)
    attn_mfma_kernel<<<dim3(16, 32), blk, 0, stream>>>(qw, kw, vw, ow);

    // split attention output, then output projection (Wo is z=3 slice)
    convert_split_kernel<<<dim3(n4 / 256), blk, 0, stream>>>(ow, OhS, OlS, n4);
    gemm_bt_split_kernel<<<dim3(8, 32, 1), blk, 0, stream>>>(
        OhS, OlS, WtH + (size_t)3 * 1024 * 1024, WtL + (size_t)3 * 1024 * 1024,
        out, out, out);
}

// Round 4
// 361.700 us; speedup vs baseline: 3.1885x; 1.1579x over previous
//
#include <hip/hip_runtime.h>
#include <hip/hip_bf16.h>
#include <math.h>

#define BB   2
#define SS   2048
#define DIM  1024
#define NH   16
#define HD   64
#define MTOT (BB * SS)   // 4096

typedef unsigned short ushortT;
typedef __attribute__((ext_vector_type(8))) short short8v;   // 8 bf16 (4 VGPRs)
typedef __attribute__((ext_vector_type(4))) float float4v;   // 4 fp32 acc

union FragU { short8v v; unsigned short us[8]; unsigned int u[4]; };

__device__ inline unsigned short f2bf(float x) {             // fp32 -> bf16 RNE
    unsigned u = __builtin_bit_cast(unsigned, x);
    u += 0x7fffu + ((u >> 16) & 1u);
    return (unsigned short)(u >> 16);
}
__device__ inline float bf2f(unsigned short h) {
    unsigned u = ((unsigned)h) << 16;
    return __builtin_bit_cast(float, u);
}
// truncation split: hi = trunc-to-bf16(x), lo = trunc-to-bf16(x - hi)
__device__ inline void split_tr(float x, unsigned short& hi, unsigned short& lo) {
    unsigned u = __builtin_bit_cast(unsigned, x);
    hi = (unsigned short)(u >> 16);
    float hf = __builtin_bit_cast(float, u & 0xffff0000u);
    lo = (unsigned short)(__builtin_bit_cast(unsigned, x - hf) >> 16);
}
__device__ inline void split4(const float4& x, short4& hi, short4& lo) {
    unsigned short h0 = f2bf(x.x), h1 = f2bf(x.y), h2 = f2bf(x.z), h3 = f2bf(x.w);
    hi = make_short4((short)h0, (short)h1, (short)h2, (short)h3);
    lo = make_short4((short)f2bf(x.x - bf2f(h0)), (short)f2bf(x.y - bf2f(h1)),
                     (short)f2bf(x.z - bf2f(h2)), (short)f2bf(x.w - bf2f(h3)));
}
// async global->LDS, 16 B per lane (dest = wave-uniform base + lane*16)
__device__ inline void gld_lds16(const void* g, void* l) {
    __builtin_amdgcn_global_load_lds(
        (const __attribute__((address_space(1))) void*)g,
        (__attribute__((address_space(3))) void*)l, 16, 0, 0);
}

// ---------------------------------------------------------------------------
// fp32 -> bf16 hi/lo elementwise split (X)
// ---------------------------------------------------------------------------
__global__ __launch_bounds__(256) void convert_split_kernel(
    const float* __restrict__ in, ushortT* __restrict__ hi, ushortT* __restrict__ lo, int n4)
{
    int t = blockIdx.x * 256 + threadIdx.x;
    if (t < n4) {
        float4 x = ((const float4*)in)[t];
        short4 h, l; split4(x, h, l);
        ((short4*)hi)[t] = h;
        ((short4*)lo)[t] = l;
    }
}

// ---------------------------------------------------------------------------
// W (1024x1024 fp32, K-major) -> W^T (bf16 hi/lo, N-major rows of K)
// ---------------------------------------------------------------------------
__global__ __launch_bounds__(256) void transpose_split_kernel(
    const float* __restrict__ W0, const float* __restrict__ W1,
    const float* __restrict__ W2, const float* __restrict__ W3,
    ushortT* __restrict__ WtH, ushortT* __restrict__ WtL)
{
    const int z = blockIdx.z;
    const float* __restrict__ W = (z == 0) ? W0 : (z == 1) ? W1 : (z == 2) ? W2 : W3;
    ushortT* H = WtH + (size_t)z * 1024 * 1024;
    ushortT* L = WtL + (size_t)z * 1024 * 1024;

    __shared__ float T[64][65];
    const int k0 = blockIdx.y * 64, n0 = blockIdx.x * 64;
    const int tid = threadIdx.x;
    const int c4 = (tid & 15) * 4;

#pragma unroll
    for (int i = 0; i < 4; i++) {
        int r = (tid >> 4) + 16 * i;
        *(float4*)&T[r][c4] = *(const float4*)(W + (size_t)(k0 + r) * 1024 + n0 + c4);
    }
    __syncthreads();
#pragma unroll
    for (int i = 0; i < 4; i++) {
        int n = (tid >> 4) + 16 * i;
        float4 vv = make_float4(T[c4 + 0][n], T[c4 + 1][n], T[c4 + 2][n], T[c4 + 3][n]);
        short4 h, l; split4(vv, h, l);
        *(short4*)&H[(size_t)(n0 + n) * 1024 + k0 + c4] = h;
        *(short4*)&L[(size_t)(n0 + n) * 1024 + k0 + c4] = l;
    }
}

// ---------------------------------------------------------------------------
// K/V fp32 (B,S,H*D) -> bf16 hi/lo 64x64 tiles in MFMA B-fragment order.
// Tile index: (b*16+h)*32 + jb. Tile layout: [frag(8)][lane(64)][j(8)] ushort.
//   K (which=0): frag=(ks*4+ct): n=kv=ct*16+l15, k=d=ks*32+quad*8+j
//   V (which=1): frag=(ks*4+dt): k=kv=ks*32+quad*8+j, n=d=dt*16+l15
// ---------------------------------------------------------------------------
__global__ __launch_bounds__(256) void kv_convert_kernel(
    const float* __restrict__ kw, const float* __restrict__ vw,
    ushortT* __restrict__ KhG, ushortT* __restrict__ KlG,
    ushortT* __restrict__ VhG, ushortT* __restrict__ VlG)
{
    const int which = blockIdx.z;
    const int jb = blockIdx.x, bh = blockIdx.y;
    const int b = bh >> 4, h = bh & 15;
    const float* __restrict__ in = which ? vw : kw;
    ushortT* __restrict__ OH = which ? VhG : KhG;
    ushortT* __restrict__ OL = which ? VlG : KlG;

    __shared__ float T[64][68];
    const int tid = threadIdx.x;
    const size_t ibase = (size_t)b * SS * DIM + (size_t)h * HD + (size_t)(jb * 64) * DIM;
    const int c4 = (tid & 15) * 4;
#pragma unroll
    for (int i = 0; i < 4; i++) {
        int r = (tid >> 4) + 16 * i;
        *(float4*)&T[r][c4] = *(const float4*)(in + (size_t)r * DIM + ibase - ibase % 1 + c4);
    }
    __syncthreads();

    ushortT* oh = OH + (size_t)(bh * 32 + jb) * 4096;
    ushortT* ol = OL + (size_t)(bh * 32 + jb) * 4096;

#pragma unroll
    for (int i = 0; i < 2; i++) {
        const int s = tid + i * 256;          // slot 0..511
        const int f = s >> 6;                 // frag 0..7
        const int lane = s & 63;
        const int ks = f >> 2, c = f & 3;     // c = ct (K) or dt (V)
        const int qd = lane >> 4, l15 = lane & 15;
        ushortT hv[8], lv[8];
        if (which == 0) {
            const int kv = c * 16 + l15;
            const int d0 = ks * 32 + qd * 8;
#pragma unroll
            for (int j = 0; j < 8; j++) split_tr(T[kv][d0 + j], hv[j], lv[j]);
        } else {
            const int d = c * 16 + l15;
            const int kv0 = ks * 32 + qd * 8;
#pragma unroll
            for (int j = 0; j < 8; j++) split_tr(T[kv0 + j][d], hv[j], lv[j]);
        }
        *(short4*)&oh[s * 8]     = *(short4*)&hv[0];
        *(short4*)&oh[s * 8 + 4] = *(short4*)&hv[4];
        *(short4*)&ol[s * 8]     = *(short4*)&lv[0];
        *(short4*)&ol[s * 8 + 4] = *(short4*)&lv[4];
    }
}

// ---------------------------------------------------------------------------
// Split-bf16 MFMA GEMM (unchanged from round 3).
// ---------------------------------------------------------------------------
__global__ __launch_bounds__(256, 2) void gemm_bt_split_kernel(
    const ushortT* __restrict__ Ah, const ushortT* __restrict__ Al,
    const ushortT* __restrict__ BtH, const ushortT* __restrict__ BtL,
    float* __restrict__ Y0, float* __restrict__ Y1, float* __restrict__ Y2)
{
    const int z = blockIdx.z;
    const ushortT* __restrict__ Bh = BtH + (size_t)z * 1024 * 1024;
    const ushortT* __restrict__ Bl = BtL + (size_t)z * 1024 * 1024;
    float* __restrict__ Y = (z == 0) ? Y0 : (z == 1) ? Y1 : Y2;

    const int K = 1024, N = 1024;
    const int m0 = blockIdx.y * 128;
    const int n0 = blockIdx.x * 128;

    __shared__ __align__(16) ushortT AhS[128 * 32];
    __shared__ __align__(16) ushortT AlS[128 * 32];
    __shared__ __align__(16) ushortT BhS[128 * 32];
    __shared__ __align__(16) ushortT BlS[128 * 32];

    const int tid  = threadIdx.x;
    const int wave = tid >> 6, lane = tid & 63;
    const int quad = lane >> 4, l15 = lane & 15;
    const int wm = wave >> 1, wn = wave & 1;

    const int s0 = tid, s1 = tid + 256;
    const int ar0 = s0 >> 2, ak0 = (s0 & 3) * 8;
    const int ar1 = s1 >> 2, ak1 = (s1 & 3) * 8;

    float4v acc[4][4];
#pragma unroll
    for (int i = 0; i < 4; i++)
#pragma unroll
        for (int j = 0; j < 4; j++) acc[i][j] = (float4v){0.f, 0.f, 0.f, 0.f};

    for (int k0 = 0; k0 < K; k0 += 32) {
        __syncthreads();
        gld_lds16(Ah + (size_t)(m0 + ar0) * K + k0 + ak0, &AhS[s0 * 8]);
        gld_lds16(Ah + (size_t)(m0 + ar1) * K + k0 + ak1, &AhS[s1 * 8]);
        gld_lds16(Al + (size_t)(m0 + ar0) * K + k0 + ak0, &AlS[s0 * 8]);
        gld_lds16(Al + (size_t)(m0 + ar1) * K + k0 + ak1, &AlS[s1 * 8]);
        gld_lds16(Bh + (size_t)(n0 + ar0) * K + k0 + ak0, &BhS[s0 * 8]);
        gld_lds16(Bh + (size_t)(n0 + ar1) * K + k0 + ak1, &BhS[s1 * 8]);
        gld_lds16(Bl + (size_t)(n0 + ar0) * K + k0 + ak0, &BlS[s0 * 8]);
        gld_lds16(Bl + (size_t)(n0 + ar1) * K + k0 + ak1, &BlS[s1 * 8]);
        __syncthreads();

        FragU ah[4], al[4], bh[4], bl[4];
#pragma unroll
        for (int t = 0; t < 4; t++) {
            ah[t].v = *(const short8v*)&AhS[(wm * 64 + t * 16 + l15) * 32 + quad * 8];
            al[t].v = *(const short8v*)&AlS[(wm * 64 + t * 16 + l15) * 32 + quad * 8];
            bh[t].v = *(const short8v*)&BhS[(wn * 64 + t * 16 + l15) * 32 + quad * 8];
            bl[t].v = *(const short8v*)&BlS[(wn * 64 + t * 16 + l15) * 32 + quad * 8];
        }
#pragma unroll
        for (int mt = 0; mt < 4; mt++)
#pragma unroll
            for (int nt = 0; nt < 4; nt++) {
                acc[mt][nt] = __builtin_amdgcn_mfma_f32_16x16x32_bf16(ah[mt].v, bh[nt].v, acc[mt][nt], 0, 0, 0);
                acc[mt][nt] = __builtin_amdgcn_mfma_f32_16x16x32_bf16(ah[mt].v, bl[nt].v, acc[mt][nt], 0, 0, 0);
                acc[mt][nt] = __builtin_amdgcn_mfma_f32_16x16x32_bf16(al[mt].v, bh[nt].v, acc[mt][nt], 0, 0, 0);
            }
    }

#pragma unroll
    for (int mt = 0; mt < 4; mt++)
#pragma unroll
        for (int r = 0; r < 4; r++) {
            const int row = m0 + wm * 64 + mt * 16 + quad * 4 + r;
            float* yp = Y + (size_t)row * N + n0 + wn * 64 + l15;
#pragma unroll
            for (int nt = 0; nt < 4; nt++)
                yp[nt * 16] = acc[mt][nt][r];
        }
}

// ---------------------------------------------------------------------------
// MFMA attention v3: pure global_load_lds staging of pre-split frag-major
// K/V tiles; P round-trip in A-frag-major packed u32 with slot-XOR swizzle
// (wave-local, no barrier); direct split-bf16 O output.
// Exact reference recurrence: O = (alpha*O + P@V)/l_new every kv step.
// ---------------------------------------------------------------------------
__global__ __launch_bounds__(256, 2) void attn_mfma_kernel(
    const float* __restrict__ q,
    const ushortT* __restrict__ KhG, const ushortT* __restrict__ KlG,
    const ushortT* __restrict__ VhG, const ushortT* __restrict__ VlG,
    ushortT* __restrict__ Oh, ushortT* __restrict__ Ol)
{
    __shared__ __align__(16) ushortT KhS[4096];
    __shared__ __align__(16) ushortT KlS[4096];
    __shared__ __align__(16) ushortT VhS[4096];
    __shared__ __align__(16) ushortT VlS[4096];
    __shared__ __align__(16) unsigned int PpS[8192];   // [frag16][slot64][j8] u32

    const int tid  = threadIdx.x;
    const int wave = tid >> 6, lane = tid & 63;
    const int quad = lane >> 4, l15 = lane & 15;
    const int bh = blockIdx.y, b = bh >> 4, h = bh & 15;
    const size_t base = (size_t)b * SS * DIM + (size_t)h * HD;
    const int qs0 = blockIdx.x * 128 + wave * 32;

    // ---- Q fragments (x 1/8 folded in; RNE split) ----
    FragU Qh[2][2], Ql[2][2];
#pragma unroll
    for (int rt = 0; rt < 2; rt++) {
        const int qrow = qs0 + rt * 16 + l15;
#pragma unroll
        for (int ks = 0; ks < 2; ks++) {
            const float* p0 = q + base + (size_t)qrow * DIM + ks * 32 + quad * 8;
            float4 a = *(const float4*)(p0);
            float4 c = *(const float4*)(p0 + 4);
            float e[8] = {a.x, a.y, a.z, a.w, c.x, c.y, c.z, c.w};
#pragma unroll
            for (int j = 0; j < 8; j++) {
                float x = e[j] * 0.125f;
                unsigned short hs = f2bf(x);
                Qh[rt][ks].us[j] = hs;
                Ql[rt][ks].us[j] = f2bf(x - bf2f(hs));
            }
        }
    }

    FragU onesF;
#pragma unroll
    for (int i = 0; i < 4; i++) onesF.u[i] = 0x3F803F80u;

    float4v Oacc[2][4];
#pragma unroll
    for (int rt = 0; rt < 2; rt++)
#pragma unroll
        for (int dt = 0; dt < 4; dt++) Oacc[rt][dt] = (float4v){0.f, 0.f, 0.f, 0.f};

    float m_run[2][4], l_run[2][4];
#pragma unroll
    for (int rt = 0; rt < 2; rt++)
#pragma unroll
        for (int r = 0; r < 4; r++) { m_run[rt][r] = -INFINITY; l_run[rt][r] = 0.f; }

    const int sl0 = wave * 128 + lane;          // staging slot for inst 0
    const int sl1 = sl0 + 64;                   // staging slot for inst 1
    const int rslot = lane ^ ((lane >> 2) & 3); // swizzled P read slot

    for (int jb = 0; jb < 32; jb++) {
        __syncthreads();   // prev-iter K/V readers done
        {
            const size_t tb = (size_t)(bh * 32 + jb) * 4096;
            gld_lds16(KhG + tb + sl0 * 8, &KhS[sl0 * 8]);
            gld_lds16(KhG + tb + sl1 * 8, &KhS[sl1 * 8]);
            gld_lds16(KlG + tb + sl0 * 8, &KlS[sl0 * 8]);
            gld_lds16(KlG + tb + sl1 * 8, &KlS[sl1 * 8]);
            gld_lds16(VhG + tb + sl0 * 8, &VhS[sl0 * 8]);
            gld_lds16(VhG + tb + sl1 * 8, &VhS[sl1 * 8]);
            gld_lds16(VlG + tb + sl0 * 8, &VlS[sl0 * 8]);
            gld_lds16(VlG + tb + sl1 * 8, &VlS[sl1 * 8]);
        }
        __syncthreads();   // drains vmcnt before use

        // ---- S = (Q/8) @ K^T : 3 split passes ----
        float4v s[2][4];
#pragma unroll
        for (int rt = 0; rt < 2; rt++)
#pragma unroll
            for (int ct = 0; ct < 4; ct++) s[rt][ct] = (float4v){0.f, 0.f, 0.f, 0.f};

#pragma unroll
        for (int ks = 0; ks < 2; ks++) {
            FragU khf[4], klf[4];
#pragma unroll
            for (int ct = 0; ct < 4; ct++) {
                khf[ct].v = *(const short8v*)&KhS[((ks * 4 + ct) * 64 + lane) * 8];
                klf[ct].v = *(const short8v*)&KlS[((ks * 4 + ct) * 64 + lane) * 8];
            }
#pragma unroll
            for (int rt = 0; rt < 2; rt++)
#pragma unroll
                for (int ct = 0; ct < 4; ct++) {
                    s[rt][ct] = __builtin_amdgcn_mfma_f32_16x16x32_bf16(Qh[rt][ks].v, khf[ct].v, s[rt][ct], 0, 0, 0);
                    s[rt][ct] = __builtin_amdgcn_mfma_f32_16x16x32_bf16(Qh[rt][ks].v, klf[ct].v, s[rt][ct], 0, 0, 0);
                    s[rt][ct] = __builtin_amdgcn_mfma_f32_16x16x32_bf16(Ql[rt][ks].v, khf[ct].v, s[rt][ct], 0, 0, 0);
                }
        }

        // ---- row stats (exact fp32 running max) ----
        float mn[2][4], al[2][4];
#pragma unroll
        for (int rt = 0; rt < 2; rt++)
#pragma unroll
            for (int r = 0; r < 4; r++) {
                float v0 = fmaxf(fmaxf(s[rt][0][r], s[rt][1][r]),
                                 fmaxf(s[rt][2][r], s[rt][3][r]));
#pragma unroll
                for (int msk = 1; msk < 16; msk <<= 1)
                    v0 = fmaxf(v0, __shfl_xor(v0, msk, 64));
                float mm = fmaxf(m_run[rt][r], v0);
                mn[rt][r] = mm;
                al[rt][r] = __expf(m_run[rt][r] - mm);
            }

        // ---- P = exp(S-mn): trunc hi/lo, packed u32 -> A-frag-major LDS ----
        // write slot: frag=(wave*2+rt)*2+(ct>>1), quad_t=(ct&1)*2+(l15>>3),
        //             slot=(quad_t*16 + quad*4 + (r^quad)), idx=frag*512+slot*8+(l15&7)
#pragma unroll
        for (int rt = 0; rt < 2; rt++)
#pragma unroll
            for (int ct = 0; ct < 4; ct++) {
                const int fbase = ((wave * 2 + rt) * 2 + (ct >> 1)) * 512
                                + (((ct & 1) * 2 + (l15 >> 3)) * 16 + quad * 4) * 8
                                + (l15 & 7);
#pragma unroll
                for (int r = 0; r < 4; r++) {
                    float p = __expf(s[rt][ct][r] - mn[rt][r]);
                    unsigned u = __builtin_bit_cast(unsigned, p);
                    float hf = __builtin_bit_cast(float, u & 0xffff0000u);
                    unsigned lo = __builtin_bit_cast(unsigned, p - hf) & 0xffff0000u;
                    PpS[fbase + (r ^ quad) * 8] = (u >> 16) | lo;
                }
            }
        // wave-local region: no barrier needed (lgkmcnt orders write->read)

        // ---- reload P as A-operand fragments ----
        FragU PhF[2][2], PlF[2][2];
#pragma unroll
        for (int rt = 0; rt < 2; rt++)
#pragma unroll
            for (int ks = 0; ks < 2; ks++) {
                const int ibase = ((wave * 2 + rt) * 2 + ks) * 512 + rslot * 8;
                uint4 r0 = *(const uint4*)&PpS[ibase];
                uint4 r1 = *(const uint4*)&PpS[ibase + 4];
                unsigned w[8] = {r0.x, r0.y, r0.z, r0.w, r1.x, r1.y, r1.z, r1.w};
#pragma unroll
                for (int t2 = 0; t2 < 4; t2++) {
                    unsigned x0 = w[2 * t2], x1 = w[2 * t2 + 1];
                    PhF[rt][ks].u[t2] = (x0 & 0xffffu) | (x1 << 16);
                    PlF[rt][ks].u[t2] = (x0 >> 16) | (x1 & 0xffff0000u);
                }
            }

        // ---- rowsum(P) via ones-column MFMA ----
        float4v co[2];
        co[0] = (float4v){0.f, 0.f, 0.f, 0.f};
        co[1] = (float4v){0.f, 0.f, 0.f, 0.f};
#pragma unroll
        for (int rt = 0; rt < 2; rt++)
#pragma unroll
            for (int ks = 0; ks < 2; ks++) {
                co[rt] = __builtin_amdgcn_mfma_f32_16x16x32_bf16(PhF[rt][ks].v, onesF.v, co[rt], 0, 0, 0);
                co[rt] = __builtin_amdgcn_mfma_f32_16x16x32_bf16(PlF[rt][ks].v, onesF.v, co[rt], 0, 0, 0);
            }

        float ln[2][4];
#pragma unroll
        for (int rt = 0; rt < 2; rt++)
#pragma unroll
            for (int r = 0; r < 4; r++)
                ln[rt][r] = al[rt][r] * l_run[rt][r] + co[rt][r];

        // ---- O = alpha*O + P@V ----
#pragma unroll
        for (int rt = 0; rt < 2; rt++)
#pragma unroll
            for (int dt = 0; dt < 4; dt++)
#pragma unroll
                for (int r = 0; r < 4; r++)
                    Oacc[rt][dt][r] *= al[rt][r];

#pragma unroll
        for (int ks = 0; ks < 2; ks++)
#pragma unroll
            for (int dt = 0; dt < 4; dt++) {
                FragU vhf, vlf;
                vhf.v = *(const short8v*)&VhS[((ks * 4 + dt) * 64 + lane) * 8];
                vlf.v = *(const short8v*)&VlS[((ks * 4 + dt) * 64 + lane) * 8];
#pragma unroll
                for (int rt = 0; rt < 2; rt++) {
                    Oacc[rt][dt] = __builtin_amdgcn_mfma_f32_16x16x32_bf16(PhF[rt][ks].v, vhf.v, Oacc[rt][dt], 0, 0, 0);
                    Oacc[rt][dt] = __builtin_amdgcn_mfma_f32_16x16x32_bf16(PhF[rt][ks].v, vlf.v, Oacc[rt][dt], 0, 0, 0);
                    Oacc[rt][dt] = __builtin_amdgcn_mfma_f32_16x16x32_bf16(PlF[rt][ks].v, vhf.v, Oacc[rt][dt], 0, 0, 0);
                }
            }

        // ---- O /= l_new (reference divides every step) ----
#pragma unroll
        for (int rt = 0; rt < 2; rt++)
#pragma unroll
            for (int r = 0; r < 4; r++) {
                float inv = 1.0f / ln[rt][r];
#pragma unroll
                for (int dt = 0; dt < 4; dt++)
                    Oacc[rt][dt][r] *= inv;
                m_run[rt][r] = mn[rt][r];
                l_run[rt][r] = ln[rt][r];
            }
    }

    // ---- store O as split bf16 (row-major (B,S,H*D) for the O-proj GEMM) ----
#pragma unroll
    for (int rt = 0; rt < 2; rt++)
#pragma unroll
        for (int r = 0; r < 4; r++) {
            const int row = qs0 + rt * 16 + quad * 4 + r;
            const size_t ob = (size_t)(b * SS + row) * DIM + h * HD + l15;
#pragma unroll
            for (int dt = 0; dt < 4; dt++) {
                unsigned short hs, ls;
                split_tr(Oacc[rt][dt][r], hs, ls);
                Oh[ob + dt * 16] = hs;
                Ol[ob + dt * 16] = ls;
            }
        }
}

// ---------------------------------------------------------------------------
extern "C" void kernel_launch(void* const* d_in, const int* in_sizes, int n_in,
                              void* d_out, int out_size, void* d_ws, size_t ws_size,
                              hipStream_t stream)
{
    const float* x  = (const float*)d_in[0];
    const float* Wq = (const float*)d_in[1];
    const float* Wk = (const float*)d_in[2];
    const float* Wv = (const float*)d_in[3];
    const float* Wo = (const float*)d_in[4];
    float* out = (float*)d_out;

    char* w = (char*)d_ws;
    float*   qw  = (float*)(w);                        // 16 MB
    float*   kw  = (float*)(w + ((size_t)16 << 20));   // 16 MB (later Oh/Ol)
    float*   vw  = (float*)(w + ((size_t)32 << 20));   // 16 MB
    ushortT* XhS = (ushortT*)(w + ((size_t)48 << 20)); // 8 MB (later VhG)
    ushortT* XlS = (ushortT*)(w + ((size_t)56 << 20)); // 8 MB (later VlG)
    ushortT* WtH = (ushortT*)(w + ((size_t)64 << 20)); // 8 MB (4 matrices)
    ushortT* WtL = (ushortT*)(w + ((size_t)72 << 20)); // 8 MB
    ushortT* KhG = (ushortT*)(w + ((size_t)80 << 20)); // 8 MB
    ushortT* KlG = (ushortT*)(w + ((size_t)88 << 20)); // 8 MB  -> 96 MB total
    ushortT* VhG = XhS;                                // reuse after QKV GEMM
    ushortT* VlG = XlS;
    ushortT* OhS = (ushortT*)kw;                       // reuse after kv_convert
    ushortT* OlS = (ushortT*)(w + ((size_t)24 << 20));

    dim3 blk(256);
    const int n4 = MTOT * DIM / 4;

    // split X -> bf16 hi/lo; transpose+split all four W
    convert_split_kernel<<<dim3(n4 / 256), blk, 0, stream>>>(x, XhS, XlS, n4);
    transpose_split_kernel<<<dim3(16, 16, 4), blk, 0, stream>>>(Wq, Wk, Wv, Wo, WtH, WtL);

    // Q/K/V projections (split-bf16 MFMA GEMM)
    gemm_bt_split_kernel<<<dim3(8, 32, 3), blk, 0, stream>>>(XhS, XlS, WtH, WtL, qw, kw, vw);

    // K/V -> frag-major split tiles
    kv_convert_kernel<<<dim3(32, 32, 2), blk, 0, stream>>>(kw, vw, KhG, KlG, VhG, VlG);

    // attention (exact reference recurrence, kv block = 64)
    attn_mfma_kernel<<<dim3(16, 32), blk, 0, stream>>>(qw, KhG, KlG, VhG, VlG, OhS, OlS);

    // output projection
    gemm_bt_split_kernel<<<dim3(8, 32, 1), blk, 0, stream>>>(
        OhS, OlS, WtH + (size_t)3 * 1024 * 1024, WtL + (size_t)3 * 1024 * 1024,
        out, out, out);
}

// Round 5
// 337.568 us; speedup vs baseline: 3.4165x; 1.0715x over previous
//
#include <hip/hip_runtime.h>
#include <hip/hip_bf16.h>
#include <math.h>

#define BB   2
#define SS   2048
#define DIM  1024
#define NH   16
#define HD   64
#define MTOT (BB * SS)   // 4096

typedef unsigned short ushortT;
typedef __attribute__((ext_vector_type(8))) short short8v;   // 8 bf16 (4 VGPRs)
typedef __attribute__((ext_vector_type(4))) float float4v;   // 4 fp32 acc

union FragU { short8v v; unsigned short us[8]; unsigned int u[4]; };

__device__ inline unsigned short f2bf(float x) {             // fp32 -> bf16 RNE
    unsigned u = __builtin_bit_cast(unsigned, x);
    u += 0x7fffu + ((u >> 16) & 1u);
    return (unsigned short)(u >> 16);
}
__device__ inline float bf2f(unsigned short h) {
    unsigned u = ((unsigned)h) << 16;
    return __builtin_bit_cast(float, u);
}
// truncation split: hi = trunc-to-bf16(x), lo = trunc-to-bf16(x - hi)
__device__ inline void split_tr(float x, unsigned short& hi, unsigned short& lo) {
    unsigned u = __builtin_bit_cast(unsigned, x);
    hi = (unsigned short)(u >> 16);
    float hf = __builtin_bit_cast(float, u & 0xffff0000u);
    lo = (unsigned short)(__builtin_bit_cast(unsigned, x - hf) >> 16);
}
__device__ inline void split4(const float4& x, short4& hi, short4& lo) {
    unsigned short h0 = f2bf(x.x), h1 = f2bf(x.y), h2 = f2bf(x.z), h3 = f2bf(x.w);
    hi = make_short4((short)h0, (short)h1, (short)h2, (short)h3);
    lo = make_short4((short)f2bf(x.x - bf2f(h0)), (short)f2bf(x.y - bf2f(h1)),
                     (short)f2bf(x.z - bf2f(h2)), (short)f2bf(x.w - bf2f(h3)));
}
// async global->LDS, 16 B per lane (dest = wave-uniform base + lane*16)
__device__ inline void gld_lds16(const void* g, void* l) {
    __builtin_amdgcn_global_load_lds(
        (const __attribute__((address_space(1))) void*)g,
        (__attribute__((address_space(3))) void*)l, 16, 0, 0);
}

// ---------------------------------------------------------------------------
// fp32 -> bf16 hi/lo elementwise split (X)
// ---------------------------------------------------------------------------
__global__ __launch_bounds__(256) void convert_split_kernel(
    const float* __restrict__ in, ushortT* __restrict__ hi, ushortT* __restrict__ lo, int n4)
{
    int t = blockIdx.x * 256 + threadIdx.x;
    if (t < n4) {
        float4 x = ((const float4*)in)[t];
        short4 h, l; split4(x, h, l);
        ((short4*)hi)[t] = h;
        ((short4*)lo)[t] = l;
    }
}

// ---------------------------------------------------------------------------
// W (1024x1024 fp32, K-major) -> W^T (bf16 hi/lo, N-major rows of K)
// ---------------------------------------------------------------------------
__global__ __launch_bounds__(256) void transpose_split_kernel(
    const float* __restrict__ W0, const float* __restrict__ W1,
    const float* __restrict__ W2, const float* __restrict__ W3,
    ushortT* __restrict__ WtH, ushortT* __restrict__ WtL)
{
    const int z = blockIdx.z;
    const float* __restrict__ W = (z == 0) ? W0 : (z == 1) ? W1 : (z == 2) ? W2 : W3;
    ushortT* H = WtH + (size_t)z * 1024 * 1024;
    ushortT* L = WtL + (size_t)z * 1024 * 1024;

    __shared__ float T[64][65];
    const int k0 = blockIdx.y * 64, n0 = blockIdx.x * 64;
    const int tid = threadIdx.x;
    const int c4 = (tid & 15) * 4;

#pragma unroll
    for (int i = 0; i < 4; i++) {
        int r = (tid >> 4) + 16 * i;
        *(float4*)&T[r][c4] = *(const float4*)(W + (size_t)(k0 + r) * 1024 + n0 + c4);
    }
    __syncthreads();
#pragma unroll
    for (int i = 0; i < 4; i++) {
        int n = (tid >> 4) + 16 * i;
        float4 vv = make_float4(T[c4 + 0][n], T[c4 + 1][n], T[c4 + 2][n], T[c4 + 3][n]);
        short4 h, l; split4(vv, h, l);
        *(short4*)&H[(size_t)(n0 + n) * 1024 + k0 + c4] = h;
        *(short4*)&L[(size_t)(n0 + n) * 1024 + k0 + c4] = l;
    }
}

// ---------------------------------------------------------------------------
// K/V fp32 (B,S,H*D) -> bf16 hi/lo 64x64 tiles, frag-major [frag8][lane64][j8].
// K frag f=ks*4+t: element (kv=t*16+l15, d=ks*32+quad*8+j)   (A-op for S^T)
// V frag f=ks*4+t: element (d=t*16+l15, kv=ks*32+quad*8+j)   (A-op V^T for PV)
// ---------------------------------------------------------------------------
__global__ __launch_bounds__(256) void kv_convert_kernel(
    const float* __restrict__ kw, const float* __restrict__ vw,
    ushortT* __restrict__ KhG, ushortT* __restrict__ KlG,
    ushortT* __restrict__ VhG, ushortT* __restrict__ VlG)
{
    const int which = blockIdx.z;
    const int jb = blockIdx.x, bh = blockIdx.y;
    const int b = bh >> 4, h = bh & 15;
    const float* __restrict__ in = which ? vw : kw;
    ushortT* __restrict__ OH = which ? VhG : KhG;
    ushortT* __restrict__ OL = which ? VlG : KlG;

    __shared__ float T[64][68];
    const int tid = threadIdx.x;
    const size_t ibase = (size_t)b * SS * DIM + (size_t)h * HD + (size_t)(jb * 64) * DIM;
    const int c4 = (tid & 15) * 4;
#pragma unroll
    for (int i = 0; i < 4; i++) {
        int r = (tid >> 4) + 16 * i;
        *(float4*)&T[r][c4] = *(const float4*)(in + ibase + (size_t)r * DIM + c4);
    }
    __syncthreads();

    ushortT* oh = OH + (size_t)(bh * 32 + jb) * 4096;
    ushortT* ol = OL + (size_t)(bh * 32 + jb) * 4096;

#pragma unroll
    for (int i = 0; i < 2; i++) {
        const int s = tid + i * 256;          // slot 0..511
        const int f = s >> 6;                 // frag 0..7
        const int lane = s & 63;
        const int ks = f >> 2, c = f & 3;
        const int qd = lane >> 4, l15 = lane & 15;
        ushortT hv[8], lv[8];
        if (which == 0) {
            const int kv = c * 16 + l15;
            const int d0 = ks * 32 + qd * 8;
#pragma unroll
            for (int j = 0; j < 8; j++) split_tr(T[kv][d0 + j], hv[j], lv[j]);
        } else {
            const int d = c * 16 + l15;
            const int kv0 = ks * 32 + qd * 8;
#pragma unroll
            for (int j = 0; j < 8; j++) split_tr(T[kv0 + j][d], hv[j], lv[j]);
        }
        *(short4*)&oh[s * 8]     = *(short4*)&hv[0];
        *(short4*)&oh[s * 8 + 4] = *(short4*)&hv[4];
        *(short4*)&ol[s * 8]     = *(short4*)&lv[0];
        *(short4*)&ol[s * 8 + 4] = *(short4*)&lv[4];
    }
}

// ---------------------------------------------------------------------------
// Split-bf16 MFMA GEMM (unchanged from round 3/4).
// ---------------------------------------------------------------------------
__global__ __launch_bounds__(256, 2) void gemm_bt_split_kernel(
    const ushortT* __restrict__ Ah, const ushortT* __restrict__ Al,
    const ushortT* __restrict__ BtH, const ushortT* __restrict__ BtL,
    float* __restrict__ Y0, float* __restrict__ Y1, float* __restrict__ Y2)
{
    const int z = blockIdx.z;
    const ushortT* __restrict__ Bh = BtH + (size_t)z * 1024 * 1024;
    const ushortT* __restrict__ Bl = BtL + (size_t)z * 1024 * 1024;
    float* __restrict__ Y = (z == 0) ? Y0 : (z == 1) ? Y1 : Y2;

    const int K = 1024, N = 1024;
    const int m0 = blockIdx.y * 128;
    const int n0 = blockIdx.x * 128;

    __shared__ __align__(16) ushortT AhS[128 * 32];
    __shared__ __align__(16) ushortT AlS[128 * 32];
    __shared__ __align__(16) ushortT BhS[128 * 32];
    __shared__ __align__(16) ushortT BlS[128 * 32];

    const int tid  = threadIdx.x;
    const int wave = tid >> 6, lane = tid & 63;
    const int quad = lane >> 4, l15 = lane & 15;
    const int wm = wave >> 1, wn = wave & 1;

    const int s0 = tid, s1 = tid + 256;
    const int ar0 = s0 >> 2, ak0 = (s0 & 3) * 8;
    const int ar1 = s1 >> 2, ak1 = (s1 & 3) * 8;

    float4v acc[4][4];
#pragma unroll
    for (int i = 0; i < 4; i++)
#pragma unroll
        for (int j = 0; j < 4; j++) acc[i][j] = (float4v){0.f, 0.f, 0.f, 0.f};

    for (int k0 = 0; k0 < K; k0 += 32) {
        __syncthreads();
        gld_lds16(Ah + (size_t)(m0 + ar0) * K + k0 + ak0, &AhS[s0 * 8]);
        gld_lds16(Ah + (size_t)(m0 + ar1) * K + k0 + ak1, &AhS[s1 * 8]);
        gld_lds16(Al + (size_t)(m0 + ar0) * K + k0 + ak0, &AlS[s0 * 8]);
        gld_lds16(Al + (size_t)(m0 + ar1) * K + k0 + ak1, &AlS[s1 * 8]);
        gld_lds16(Bh + (size_t)(n0 + ar0) * K + k0 + ak0, &BhS[s0 * 8]);
        gld_lds16(Bh + (size_t)(n0 + ar1) * K + k0 + ak1, &BhS[s1 * 8]);
        gld_lds16(Bl + (size_t)(n0 + ar0) * K + k0 + ak0, &BlS[s0 * 8]);
        gld_lds16(Bl + (size_t)(n0 + ar1) * K + k0 + ak1, &BlS[s1 * 8]);
        __syncthreads();

        FragU ah[4], al[4], bh[4], bl[4];
#pragma unroll
        for (int t = 0; t < 4; t++) {
            ah[t].v = *(const short8v*)&AhS[(wm * 64 + t * 16 + l15) * 32 + quad * 8];
            al[t].v = *(const short8v*)&AlS[(wm * 64 + t * 16 + l15) * 32 + quad * 8];
            bh[t].v = *(const short8v*)&BhS[(wn * 64 + t * 16 + l15) * 32 + quad * 8];
            bl[t].v = *(const short8v*)&BlS[(wn * 64 + t * 16 + l15) * 32 + quad * 8];
        }
#pragma unroll
        for (int mt = 0; mt < 4; mt++)
#pragma unroll
            for (int nt = 0; nt < 4; nt++) {
                acc[mt][nt] = __builtin_amdgcn_mfma_f32_16x16x32_bf16(ah[mt].v, bh[nt].v, acc[mt][nt], 0, 0, 0);
                acc[mt][nt] = __builtin_amdgcn_mfma_f32_16x16x32_bf16(ah[mt].v, bl[nt].v, acc[mt][nt], 0, 0, 0);
                acc[mt][nt] = __builtin_amdgcn_mfma_f32_16x16x32_bf16(al[mt].v, bh[nt].v, acc[mt][nt], 0, 0, 0);
            }
    }

#pragma unroll
    for (int mt = 0; mt < 4; mt++)
#pragma unroll
        for (int r = 0; r < 4; r++) {
            const int row = m0 + wm * 64 + mt * 16 + quad * 4 + r;
            float* yp = Y + (size_t)row * N + n0 + wn * 64 + l15;
#pragma unroll
            for (int nt = 0; nt < 4; nt++)
                yp[nt * 16] = acc[mt][nt][r];
        }
}

// ---------------------------------------------------------------------------
// MFMA attention v4 (S^T orientation): S^T = K·Q^T so q = C-column (lane&15).
// Per-lane row stats (2 shuffles), exp2-domain softmax, P^T written b64 into
// B-frag layout (wave-local, no barrier), PV as V^T·P^T. Exact reference
// recurrence: O = (alpha*O + P@V)/l_new EVERY kv step (semantic; not
// deferral-equivalent). Split-bf16 (hi+lo) 3-pass MFMA throughout.
// ---------------------------------------------------------------------------
__global__ __launch_bounds__(256, 2) void attn_mfma_kernel(
    const float* __restrict__ q,
    const ushortT* __restrict__ KhG, const ushortT* __restrict__ KlG,
    const ushortT* __restrict__ VhG, const ushortT* __restrict__ VlG,
    ushortT* __restrict__ Oh, ushortT* __restrict__ Ol)
{
    __shared__ __align__(16) ushortT KhS[4096];
    __shared__ __align__(16) ushortT KlS[4096];
    __shared__ __align__(16) ushortT VhS[4096];
    __shared__ __align__(16) ushortT VlS[4096];
    __shared__ __align__(16) ushortT PW[4][2][2048];   // [wave][hi/lo][frag4*slot64*j8]

    const int tid  = threadIdx.x;
    const int wave = tid >> 6, lane = tid & 63;
    const int quad = lane >> 4, l15 = lane & 15;
    const int bh = blockIdx.y, b = bh >> 4, h = bh & 15;
    const size_t base = (size_t)b * SS * DIM + (size_t)h * HD;
    const int qs0 = blockIdx.x * 128 + wave * 32;

    // ---- Q fragments: scale = 1/8 * log2(e) folded in (exp2 domain) ----
    const float qscale = 0.125f * 1.4426950408889634f;
    FragU Qh[2][2], Ql[2][2];
#pragma unroll
    for (int rt = 0; rt < 2; rt++) {
        const int qrow = qs0 + rt * 16 + l15;
#pragma unroll
        for (int ks = 0; ks < 2; ks++) {
            const float* p0 = q + base + (size_t)qrow * DIM + ks * 32 + quad * 8;
            float4 a = *(const float4*)(p0);
            float4 c = *(const float4*)(p0 + 4);
            float e[8] = {a.x, a.y, a.z, a.w, c.x, c.y, c.z, c.w};
#pragma unroll
            for (int j = 0; j < 8; j++) {
                float x = e[j] * qscale;
                unsigned short hs = f2bf(x);
                Qh[rt][ks].us[j] = hs;
                Ql[rt][ks].us[j] = f2bf(x - bf2f(hs));
            }
        }
    }

    FragU onesF;
#pragma unroll
    for (int i = 0; i < 4; i++) onesF.u[i] = 0x3F803F80u;

    float4v Oacc[4][2];   // [dt][rt], O^T layout: row d=dt*16+quad*4+r, col q=rt*16+l15
#pragma unroll
    for (int dt = 0; dt < 4; dt++)
#pragma unroll
        for (int rt = 0; rt < 2; rt++) Oacc[dt][rt] = (float4v){0.f, 0.f, 0.f, 0.f};

    float m_run[2] = {-INFINITY, -INFINITY};
    float l_run[2] = {0.f, 0.f};

    const int sl0 = wave * 128 + lane, sl1 = sl0 + 64;
    ushortT* ph = &PW[wave][0][0];
    ushortT* pl = &PW[wave][1][0];
    // P write base: frag=rt*2+(mt>>1), slot=((mt&1)*2+(quad>>1))*16+l15, j0=(quad&1)*4
    const int pwq = ((quad >> 1) * 16 + l15) * 8 + (quad & 1) * 4;

    for (int jb = 0; jb < 32; jb++) {
        __syncthreads();   // prev-iter K/V readers done
        {
            const size_t tb = (size_t)(bh * 32 + jb) * 4096;
            gld_lds16(KhG + tb + sl0 * 8, &KhS[sl0 * 8]);
            gld_lds16(KhG + tb + sl1 * 8, &KhS[sl1 * 8]);
            gld_lds16(KlG + tb + sl0 * 8, &KlS[sl0 * 8]);
            gld_lds16(KlG + tb + sl1 * 8, &KlS[sl1 * 8]);
            gld_lds16(VhG + tb + sl0 * 8, &VhS[sl0 * 8]);
            gld_lds16(VhG + tb + sl1 * 8, &VhS[sl1 * 8]);
            gld_lds16(VlG + tb + sl0 * 8, &VlS[sl0 * 8]);
            gld_lds16(VlG + tb + sl1 * 8, &VlS[sl1 * 8]);
        }
        __syncthreads();   // drains vmcnt before use

        // ---- S^T = K @ Q^T (3 split passes); C: row=kv=mt*16+quad*4+r, col=q=l15 ----
        float4v st[4][2];
#pragma unroll
        for (int mt = 0; mt < 4; mt++)
#pragma unroll
            for (int rt = 0; rt < 2; rt++) st[mt][rt] = (float4v){0.f, 0.f, 0.f, 0.f};

#pragma unroll
        for (int ks = 0; ks < 2; ks++) {
            FragU kh[4], kl[4];
#pragma unroll
            for (int mt = 0; mt < 4; mt++) {
                kh[mt].v = *(const short8v*)&KhS[((ks * 4 + mt) * 64 + lane) * 8];
                kl[mt].v = *(const short8v*)&KlS[((ks * 4 + mt) * 64 + lane) * 8];
            }
#pragma unroll
            for (int mt = 0; mt < 4; mt++)
#pragma unroll
                for (int rt = 0; rt < 2; rt++) {
                    st[mt][rt] = __builtin_amdgcn_mfma_f32_16x16x32_bf16(kh[mt].v, Qh[rt][ks].v, st[mt][rt], 0, 0, 0);
                    st[mt][rt] = __builtin_amdgcn_mfma_f32_16x16x32_bf16(kh[mt].v, Ql[rt][ks].v, st[mt][rt], 0, 0, 0);
                    st[mt][rt] = __builtin_amdgcn_mfma_f32_16x16x32_bf16(kl[mt].v, Qh[rt][ks].v, st[mt][rt], 0, 0, 0);
                }
        }

        // ---- per-column (q) stats: local 16-max + 2 cross-quad shuffles ----
        float mn[2], al[2];
#pragma unroll
        for (int rt = 0; rt < 2; rt++) {
            float v0 = fmaxf(fmaxf(st[0][rt][0], st[0][rt][1]), fmaxf(st[0][rt][2], st[0][rt][3]));
#pragma unroll
            for (int mt = 1; mt < 4; mt++) {
                float v1 = fmaxf(fmaxf(st[mt][rt][0], st[mt][rt][1]), fmaxf(st[mt][rt][2], st[mt][rt][3]));
                v0 = fmaxf(v0, v1);
            }
            v0 = fmaxf(v0, __shfl_xor(v0, 16, 64));
            v0 = fmaxf(v0, __shfl_xor(v0, 32, 64));
            mn[rt] = fmaxf(m_run[rt], v0);
            al[rt] = __builtin_amdgcn_exp2f(m_run[rt] - mn[rt]);   // 0 on first iter
        }

        // ---- P^T = exp2(S^T - mn) in-place ----
#pragma unroll
        for (int mt = 0; mt < 4; mt++)
#pragma unroll
            for (int rt = 0; rt < 2; rt++)
#pragma unroll
                for (int r = 0; r < 4; r++)
                    st[mt][rt][r] = __builtin_amdgcn_exp2f(st[mt][rt][r] - mn[rt]);

        // ---- write P^T hi/lo as b64 into B-frag layout (wave-local) ----
#pragma unroll
        for (int rt = 0; rt < 2; rt++)
#pragma unroll
            for (int mt = 0; mt < 4; mt++) {
                unsigned u0 = __builtin_bit_cast(unsigned, st[mt][rt][0]);
                unsigned u1 = __builtin_bit_cast(unsigned, st[mt][rt][1]);
                unsigned u2 = __builtin_bit_cast(unsigned, st[mt][rt][2]);
                unsigned u3 = __builtin_bit_cast(unsigned, st[mt][rt][3]);
                unsigned h01 = (u0 >> 16) | (u1 & 0xffff0000u);
                unsigned h23 = (u2 >> 16) | (u3 & 0xffff0000u);
                float d0 = st[mt][rt][0] - __builtin_bit_cast(float, u0 & 0xffff0000u);
                float d1 = st[mt][rt][1] - __builtin_bit_cast(float, u1 & 0xffff0000u);
                float d2 = st[mt][rt][2] - __builtin_bit_cast(float, u2 & 0xffff0000u);
                float d3 = st[mt][rt][3] - __builtin_bit_cast(float, u3 & 0xffff0000u);
                unsigned l01 = (__builtin_bit_cast(unsigned, d0) >> 16) |
                               (__builtin_bit_cast(unsigned, d1) & 0xffff0000u);
                unsigned l23 = (__builtin_bit_cast(unsigned, d2) >> 16) |
                               (__builtin_bit_cast(unsigned, d3) & 0xffff0000u);
                const int idx = ((rt * 2 + (mt >> 1)) * 512 + (mt & 1) * 256) + pwq;
                *(uint2*)&ph[idx] = make_uint2(h01, h23);
                *(uint2*)&pl[idx] = make_uint2(l01, l23);
            }
        // wave-local region: lgkmcnt orders write->read, no barrier

        // ---- reload P^T as B-operand fragments (linear b128, no repack) ----
        FragU Ph[2][2], Pl[2][2];
#pragma unroll
        for (int rt = 0; rt < 2; rt++)
#pragma unroll
            for (int ks = 0; ks < 2; ks++) {
                Ph[rt][ks].v = *(const short8v*)&ph[((rt * 2 + ks) * 64 + lane) * 8];
                Pl[rt][ks].v = *(const short8v*)&pl[((rt * 2 + ks) * 64 + lane) * 8];
            }

        // ---- column sum via ones-MFMA (rows all equal) ----
        float4v co[2];
        co[0] = (float4v){0.f, 0.f, 0.f, 0.f};
        co[1] = (float4v){0.f, 0.f, 0.f, 0.f};
#pragma unroll
        for (int rt = 0; rt < 2; rt++)
#pragma unroll
            for (int ks = 0; ks < 2; ks++) {
                co[rt] = __builtin_amdgcn_mfma_f32_16x16x32_bf16(onesF.v, Ph[rt][ks].v, co[rt], 0, 0, 0);
                co[rt] = __builtin_amdgcn_mfma_f32_16x16x32_bf16(onesF.v, Pl[rt][ks].v, co[rt], 0, 0, 0);
            }

        float ln[2];
#pragma unroll
        for (int rt = 0; rt < 2; rt++)
            ln[rt] = al[rt] * l_run[rt] + co[rt][0];

        // ---- O^T = alpha*O^T + V^T @ P^T ----
#pragma unroll
        for (int dt = 0; dt < 4; dt++)
#pragma unroll
            for (int rt = 0; rt < 2; rt++)
#pragma unroll
                for (int r = 0; r < 4; r++)
                    Oacc[dt][rt][r] *= al[rt];

#pragma unroll
        for (int ks = 0; ks < 2; ks++)
#pragma unroll
            for (int dt = 0; dt < 4; dt++) {
                FragU vh, vl;
                vh.v = *(const short8v*)&VhS[((ks * 4 + dt) * 64 + lane) * 8];
                vl.v = *(const short8v*)&VlS[((ks * 4 + dt) * 64 + lane) * 8];
#pragma unroll
                for (int rt = 0; rt < 2; rt++) {
                    Oacc[dt][rt] = __builtin_amdgcn_mfma_f32_16x16x32_bf16(vh.v, Ph[rt][ks].v, Oacc[dt][rt], 0, 0, 0);
                    Oacc[dt][rt] = __builtin_amdgcn_mfma_f32_16x16x32_bf16(vl.v, Ph[rt][ks].v, Oacc[dt][rt], 0, 0, 0);
                    Oacc[dt][rt] = __builtin_amdgcn_mfma_f32_16x16x32_bf16(vh.v, Pl[rt][ks].v, Oacc[dt][rt], 0, 0, 0);
                }
            }

        // ---- O /= l_new (reference divides every step) ----
#pragma unroll
        for (int rt = 0; rt < 2; rt++) {
            float inv = __builtin_amdgcn_rcpf(ln[rt]);
#pragma unroll
            for (int dt = 0; dt < 4; dt++)
#pragma unroll
                for (int r = 0; r < 4; r++)
                    Oacc[dt][rt][r] *= inv;
            m_run[rt] = mn[rt];
            l_run[rt] = ln[rt];
        }
    }

    // ---- epilogue: transpose O^T via wave-local LDS, split-bf16 coalesced store ----
    float* Pf = (float*)&PW[wave][0][0];   // 2048 floats available, use 1088
    const int q16 = lane >> 2, c = lane & 3;
#pragma unroll
    for (int rt = 0; rt < 2; rt++) {
#pragma unroll
        for (int dt = 0; dt < 4; dt++)
            *(float4v*)&Pf[l15 * 68 + dt * 16 + quad * 4] = Oacc[dt][rt];
        float vals[16];
#pragma unroll
        for (int kk = 0; kk < 4; kk++)
            *(float4v*)&vals[kk * 4] = *(const float4v*)&Pf[q16 * 68 + c * 16 + kk * 4];

        unsigned ho[8], lo8[8];
#pragma unroll
        for (int kk = 0; kk < 8; kk++) {
            unsigned short h0, l0, h1, l1;
            split_tr(vals[2 * kk], h0, l0);
            split_tr(vals[2 * kk + 1], h1, l1);
            ho[kk]  = (unsigned)h0 | ((unsigned)h1 << 16);
            lo8[kk] = (unsigned)l0 | ((unsigned)l1 << 16);
        }
        const int qrow = qs0 + rt * 16 + q16;
        const size_t off = (size_t)(b * SS + qrow) * DIM + h * HD + c * 16;
        *(uint4*)&Oh[off]     = make_uint4(ho[0], ho[1], ho[2], ho[3]);
        *(uint4*)&Oh[off + 8] = make_uint4(ho[4], ho[5], ho[6], ho[7]);
        *(uint4*)&Ol[off]     = make_uint4(lo8[0], lo8[1], lo8[2], lo8[3]);
        *(uint4*)&Ol[off + 8] = make_uint4(lo8[4], lo8[5], lo8[6], lo8[7]);
    }
}

// ---------------------------------------------------------------------------
extern "C" void kernel_launch(void* const* d_in, const int* in_sizes, int n_in,
                              void* d_out, int out_size, void* d_ws, size_t ws_size,
                              hipStream_t stream)
{
    const float* x  = (const float*)d_in[0];
    const float* Wq = (const float*)d_in[1];
    const float* Wk = (const float*)d_in[2];
    const float* Wv = (const float*)d_in[3];
    const float* Wo = (const float*)d_in[4];
    float* out = (float*)d_out;

    char* w = (char*)d_ws;
    float*   qw  = (float*)(w);                        // 16 MB
    float*   kw  = (float*)(w + ((size_t)16 << 20));   // 16 MB (later Oh/Ol)
    float*   vw  = (float*)(w + ((size_t)32 << 20));   // 16 MB
    ushortT* XhS = (ushortT*)(w + ((size_t)48 << 20)); // 8 MB (later VhG)
    ushortT* XlS = (ushortT*)(w + ((size_t)56 << 20)); // 8 MB (later VlG)
    ushortT* WtH = (ushortT*)(w + ((size_t)64 << 20)); // 8 MB (4 matrices)
    ushortT* WtL = (ushortT*)(w + ((size_t)72 << 20)); // 8 MB
    ushortT* KhG = (ushortT*)(w + ((size_t)80 << 20)); // 8 MB
    ushortT* KlG = (ushortT*)(w + ((size_t)88 << 20)); // 8 MB  -> 96 MB total
    ushortT* VhG = XhS;                                // reuse after QKV GEMM
    ushortT* VlG = XlS;
    ushortT* OhS = (ushortT*)kw;                       // reuse after kv_convert
    ushortT* OlS = (ushortT*)(w + ((size_t)24 << 20));

    dim3 blk(256);
    const int n4 = MTOT * DIM / 4;

    // split X -> bf16 hi/lo; transpose+split all four W
    convert_split_kernel<<<dim3(n4 / 256), blk, 0, stream>>>(x, XhS, XlS, n4);
    transpose_split_kernel<<<dim3(16, 16, 4), blk, 0, stream>>>(Wq, Wk, Wv, Wo, WtH, WtL);

    // Q/K/V projections (split-bf16 MFMA GEMM)
    gemm_bt_split_kernel<<<dim3(8, 32, 3), blk, 0, stream>>>(XhS, XlS, WtH, WtL, qw, kw, vw);

    // K/V -> frag-major split tiles
    kv_convert_kernel<<<dim3(32, 32, 2), blk, 0, stream>>>(kw, vw, KhG, KlG, VhG, VlG);

    // attention (exact reference recurrence, kv block = 64)
    attn_mfma_kernel<<<dim3(16, 32), blk, 0, stream>>>(qw, KhG, KlG, VhG, VlG, OhS, OlS);

    // output projection
    gemm_bt_split_kernel<<<dim3(8, 32, 1), blk, 0, stream>>>(
        OhS, OlS, WtH + (size_t)3 * 1024 * 1024, WtL + (size_t)3 * 1024 * 1024,
        out, out, out);
}